// Round 3
// baseline (1845.034 us; speedup 1.0000x reference)
//
#include <hip/hip_runtime.h>
#include <hip/hip_bf16.h>

#define DEV static __device__ __forceinline__

constexpr int F1 = 128;   // input features
constexpr int H1 = 8;     // heads layer1
constexpr int C  = 64;    // channels per head
constexpr int B  = 64;    // graphs
constexpr int K  = 10;    // classes
constexpr float NEG = 0.2f;

DEV float b2f(__hip_bfloat16 x) { return __bfloat162float(x); }

DEV void atomicMaxF(float* a, float v) {
  if (v >= 0.f) atomicMax((int*)a, __float_as_int(v));
  else          atomicMin((unsigned int*)a, __float_as_uint(v));
}

// ---------- dtype detection + canonicalization ----------
// If the float tensors are really float32 and we reinterpret as bf16, the
// even-index halves are f32 low-mantissa bits with ~uniform exponents: ~45%
// of them are |v|>1e4 or NaN. Genuine bf16 N(0,1) data: none are.
__global__ void detect_kernel(const void* xraw, int* flag) {
  const __hip_bfloat16* xb = (const __hip_bfloat16*)xraw;
  int lane = threadIdx.x & 63;
  int bad = 0;
  for (int it = 0; it < 8; ++it) {
    int i = it * 64 + lane;
    float v = b2f(xb[2 * i]);
    if (!(fabsf(v) < 1e4f)) bad++;       // catches NaN/inf/huge
  }
  for (int off = 32; off; off >>= 1) bad += __shfl_down(bad, off);
  if (lane == 0) *flag = (bad < 64) ? 1 : 0;   // 1 = bf16, 0 = f32
}

__global__ void convert_kernel(const void* __restrict__ raw,
                               float* __restrict__ dst, int n,
                               const int* __restrict__ flag) {
  int isbf = *flag;
  for (int i = blockIdx.x * blockDim.x + threadIdx.x; i < n;
       i += gridDim.x * blockDim.x) {
    dst[i] = isbf ? b2f(((const __hip_bfloat16*)raw)[i])
                  : ((const float*)raw)[i];
  }
}

__global__ void fill_kernel(float* __restrict__ p, int n, float v) {
  int i = blockIdx.x * blockDim.x + threadIdx.x;
  if (i < n) p[i] = v;
}

// ---------- layer GEMMs ----------
// h1[n,512] = x[n,0:128] @ W1[128,512]; 8 nodes per block (amortize W reads).
__global__ void gemm1_kernel(const float* __restrict__ x,
                             const float* __restrict__ W,
                             float* __restrict__ out, int N) {
  __shared__ float xs[8][F1];
  int n0 = blockIdx.x * 8;
  int t = threadIdx.x;                 // 256
  for (int j = 0; j < 4; ++j) {
    int idx = t + j * 256;             // 1024 loads
    xs[idx >> 7][idx & 127] = x[(size_t)n0 * F1 + idx];
  }
  __syncthreads();
  float a0[8] = {}, a1[8] = {};
  for (int k = 0; k < F1; ++k) {
    float w0 = W[k * 512 + t];
    float w1 = W[k * 512 + t + 256];
#pragma unroll
    for (int j = 0; j < 8; ++j) {
      a0[j] += xs[j][k] * w0;
      a1[j] += xs[j][k] * w1;
    }
  }
#pragma unroll
  for (int j = 0; j < 8; ++j) {
    out[(size_t)(n0 + j) * 512 + t]       = a0[j];
    out[(size_t)(n0 + j) * 512 + t + 256] = a1[j];
  }
}

// h2[n,64] = x2[n,0:512] @ W2[512,64]; 4 nodes per wave, 16 per block.
__global__ void gemm2_kernel(const float* __restrict__ x2,
                             const float* __restrict__ W,
                             float* __restrict__ out, int N) {
  int wave = threadIdx.x >> 6, lane = threadIdx.x & 63;
  int n0 = (blockIdx.x * 4 + wave) * 4;
  if (n0 >= N) return;
  float acc[4] = {};
  for (int k = 0; k < 512; ++k) {
    float wv = W[k * 64 + lane];
#pragma unroll
    for (int j = 0; j < 4; ++j) acc[j] += x2[(size_t)(n0 + j) * 512 + k] * wv;
  }
#pragma unroll
  for (int j = 0; j < 4; ++j) out[(size_t)(n0 + j) * 64 + lane] = acc[j];
}

// ---------- attention ----------
template <int H>
__global__ void attn_coef_kernel(const float* __restrict__ h,
                                 const float* __restrict__ att_src,
                                 const float* __restrict__ att_dst,
                                 float* __restrict__ a_s, float* __restrict__ a_d,
                                 int N) {
  int wave = threadIdx.x >> 6, lane = threadIdx.x & 63;
  int n = blockIdx.x * 4 + wave;
  if (n >= N) return;
  for (int hh = 0; hh < H; ++hh) {
    float v  = h[(size_t)n * (H * 64) + hh * 64 + lane];
    float ps = v * att_src[hh * 64 + lane];
    float pd = v * att_dst[hh * 64 + lane];
    for (int off = 32; off; off >>= 1) {
      ps += __shfl_down(ps, off);
      pd += __shfl_down(pd, off);
    }
    if (lane == 0) {
      a_s[(size_t)n * H + hh] = ps;
      a_d[(size_t)n * H + hh] = pd;
    }
  }
}

template <int H>
__global__ void edge_max_kernel(const int* __restrict__ ei, int E, int Etot,
                                const float* __restrict__ a_s,
                                const float* __restrict__ a_d,
                                float* __restrict__ m, float* __restrict__ lk) {
  int e = blockIdx.x * blockDim.x + threadIdx.x;
  if (e >= Etot) return;
  int s, d;
  if (e < E) { s = ei[e]; d = ei[E + e]; } else { s = d = e - E; }
  for (int hh = 0; hh < H; ++hh) {
    float v = a_s[(size_t)s * H + hh] + a_d[(size_t)d * H + hh];
    v = v > 0.f ? v : NEG * v;
    lk[(size_t)e * H + hh] = v;
    atomicMaxF(&m[(size_t)d * H + hh], v);
  }
}

template <int H>
__global__ void edge_expsum_kernel(const int* __restrict__ ei, int E, int Etot,
                                   const float* __restrict__ m,
                                   float* __restrict__ lk,
                                   float* __restrict__ denom) {
  int e = blockIdx.x * blockDim.x + threadIdx.x;
  if (e >= Etot) return;
  int d = (e < E) ? ei[E + e] : e - E;
  for (int hh = 0; hh < H; ++hh) {
    float ex = __expf(lk[(size_t)e * H + hh] - m[(size_t)d * H + hh]);
    lk[(size_t)e * H + hh] = ex;
    unsafeAtomicAdd(&denom[(size_t)d * H + hh], ex);
  }
}

template <int H>
__global__ void edge_agg_kernel(const int* __restrict__ ei, int E, int Etot,
                                const float* __restrict__ lk,
                                const float* __restrict__ denom,
                                const float* __restrict__ h,
                                float* __restrict__ out) {
  int wave = threadIdx.x >> 6, lane = threadIdx.x & 63;
  int e = blockIdx.x * 4 + wave;
  if (e >= Etot) return;
  int s, d;
  if (e < E) { s = ei[e]; d = ei[E + e]; } else { s = d = e - E; }
  for (int hh = 0; hh < H; ++hh) {
    float alpha = lk[(size_t)e * H + hh] / (denom[(size_t)d * H + hh] + 1e-16f);
    float v = alpha * h[(size_t)s * (H * 64) + hh * 64 + lane];
    unsafeAtomicAdd(&out[(size_t)d * (H * 64) + hh * 64 + lane], v);
  }
}

template <int CBITS>
__global__ void bias_elu_kernel(float* __restrict__ a,
                                const float* __restrict__ bias,
                                int total) {
  int i = blockIdx.x * blockDim.x + threadIdx.x;
  if (i >= total) return;
  float v = a[i] + bias[i & ((1 << CBITS) - 1)];
  a[i] = v > 0.f ? v : (__expf(v) - 1.f);
}

__global__ void elu_pool_kernel(const float* __restrict__ out2,
                                const float* __restrict__ b2v,
                                const int* __restrict__ batch,
                                float* __restrict__ pooled, int N) {
  int wave = threadIdx.x >> 6, lane = threadIdx.x & 63;
  int seg = blockIdx.x * 4 + wave;
  int start = seg * 128;
  if (start >= N) return;
  int end = min(start + 128, N);
  float bb = b2v[lane];
  int cur = batch[start];
  float acc = 0.f;
  for (int n = start; n < end; ++n) {
    int bn = batch[n];
    if (bn != cur) {
      unsafeAtomicAdd(&pooled[cur * 64 + lane], acc);
      acc = 0.f; cur = bn;
    }
    float v = out2[(size_t)n * 64 + lane] + bb;
    v = v > 0.f ? v : (__expf(v) - 1.f);
    acc += v;
  }
  unsafeAtomicAdd(&pooled[cur * 64 + lane], acc);
}

__global__ void head_kernel(const float* __restrict__ pooled,
                            const float* __restrict__ lin1_w,
                            const float* __restrict__ lin1_b,
                            const float* __restrict__ lin2_w,
                            const float* __restrict__ lin2_b,
                            const int* __restrict__ flag,
                            void* __restrict__ outv) {
  __shared__ float P[B * C];
  __shared__ float Z[B * C];
  __shared__ float L[B * K];
  int t = threadIdx.x;  // 512
  for (int i = t; i < B * C; i += 512) P[i] = pooled[i];
  __syncthreads();
  for (int i = t; i < B * C; i += 512) {
    int r = i >> 6, c = i & 63;
    float acc = lin1_b[c];
    for (int k = 0; k < C; ++k) acc += P[r * C + k] * lin1_w[k * C + c];
    Z[i] = acc > 0.f ? acc : (__expf(acc) - 1.f);
  }
  __syncthreads();
  for (int i = t; i < B * K; i += 512) {
    int r = i / K, c = i - r * K;
    float acc = lin2_b[c];
    for (int k = 0; k < C; ++k) acc += Z[r * C + k] * lin2_w[k * K + c];
    L[i] = acc;
  }
  __syncthreads();
  if (t < B) {
    float mx = -1e30f;
    for (int c = 0; c < K; ++c) mx = fmaxf(mx, L[t * K + c]);
    float s = 0.f;
    for (int c = 0; c < K; ++c) s += __expf(L[t * K + c] - mx);
    float lse = mx + __logf(s);
    int isbf = *flag;
    for (int c = 0; c < K; ++c) {
      float val = L[t * K + c] - lse;
      if (isbf) ((__hip_bfloat16*)outv)[t * K + c] = __float2bfloat16(val);
      else      ((float*)outv)[t * K + c] = val;
    }
  }
}

extern "C" void kernel_launch(void* const* d_in, const int* in_sizes, int n_in,
                              void* d_out, int out_size, void* d_ws, size_t ws_size,
                              hipStream_t stream) {
  const void* x_raw    = d_in[0];
  const int*  ei       = (const int*)d_in[1];
  const int*  batch    = (const int*)d_in[2];

  const int N    = in_sizes[2];
  const int E    = in_sizes[1] / 2;
  const int Etot = E + N;

  int*   flag = (int*)d_ws;
  float* ws   = (float*)d_ws;
  size_t off  = 16;                       // flag + pad

  float* xw   = ws + off; off += (size_t)N * F1;        // 6.4M
  float* W1f  = ws + off; off += 128 * 512;
  float* as1w = ws + off; off += 512;
  float* ad1w = ws + off; off += 512;
  float* b1w  = ws + off; off += 512;
  float* W2f  = ws + off; off += 512 * 64;
  float* as2w = ws + off; off += 64;
  float* ad2w = ws + off; off += 64;
  float* b2w  = ws + off; off += 64;
  float* l1w  = ws + off; off += 64 * 64;
  float* l1b  = ws + off; off += 64;
  float* l2w  = ws + off; off += 640;
  float* l2b  = ws + off; off += 16;

  float* h1   = ws + off; off += (size_t)N * 512;       // 25.6M
  float* out1 = ws + off; off += (size_t)N * 512;       // 25.6M
  float* as1  = ws + off; off += (size_t)N * H1;
  float* ad1  = ws + off; off += (size_t)N * H1;
  float* m1   = ws + off; off += (size_t)N * H1;
  float* dn1  = ws + off; off += (size_t)N * H1;
  float* lk1  = ws + off; off += (size_t)Etot * H1;
  // layer-2 feature buffers alias xw (x is dead AFTER gemm1 — so any init of
  // these regions must be stream-ordered after gemm1_kernel!)
  float* h2   = xw;                                     // N*64
  float* out2 = xw + (size_t)N * 64;                    // N*64
  float* as2  = ws + off; off += (size_t)N;
  float* ad2  = ws + off; off += (size_t)N;
  float* m2   = ws + off; off += (size_t)N;
  float* dn2  = ws + off; off += (size_t)N;
  float* lk2  = ws + off; off += (size_t)Etot;
  float* pooled = ws + off; off += (size_t)B * C;

  // ---- dtype detect + canonicalize all float inputs to f32 ----
  detect_kernel<<<1, 64, 0, stream>>>(x_raw, flag);
  auto conv = [&](const void* raw, float* dst, int n) {
    int grid = (n + 255) / 256; if (grid > 8192) grid = 8192;
    convert_kernel<<<grid, 256, 0, stream>>>(raw, dst, n, flag);
  };
  conv(d_in[0],  xw,   in_sizes[0]);
  conv(d_in[3],  W1f,  in_sizes[3]);
  conv(d_in[4],  as1w, in_sizes[4]);
  conv(d_in[5],  ad1w, in_sizes[5]);
  conv(d_in[6],  b1w,  in_sizes[6]);
  conv(d_in[7],  W2f,  in_sizes[7]);
  conv(d_in[8],  as2w, in_sizes[8]);
  conv(d_in[9],  ad2w, in_sizes[9]);
  conv(d_in[10], b2w,  in_sizes[10]);
  conv(d_in[11], l1w,  in_sizes[11]);
  conv(d_in[12], l1b,  in_sizes[12]);
  conv(d_in[13], l2w,  in_sizes[13]);
  conv(d_in[14], l2b,  in_sizes[14]);

  // ---- zero / init accumulators (NOT the ones aliasing xw!) ----
  hipMemsetAsync(out1, 0, (size_t)N * 512 * 4, stream);
  hipMemsetAsync(dn1,  0, (size_t)N * H1 * 4,  stream);
  hipMemsetAsync(dn2,  0, (size_t)N * 4,       stream);
  hipMemsetAsync(pooled, 0, (size_t)B * C * 4, stream);
  fill_kernel<<<(N * H1 + 255) / 256, 256, 0, stream>>>(m1, N * H1, -1e30f);
  fill_kernel<<<(N + 255) / 256, 256, 0, stream>>>(m2, N, -1e30f);

  // ---- layer 1 ----
  gemm1_kernel<<<N / 8, 256, 0, stream>>>(xw, W1f, h1, N);
  attn_coef_kernel<H1><<<(N + 3) / 4, 256, 0, stream>>>(h1, as1w, ad1w, as1, ad1, N);
  edge_max_kernel<H1><<<(Etot + 255) / 256, 256, 0, stream>>>(ei, E, Etot, as1, ad1, m1, lk1);
  edge_expsum_kernel<H1><<<(Etot + 255) / 256, 256, 0, stream>>>(ei, E, Etot, m1, lk1, dn1);
  edge_agg_kernel<H1><<<(Etot + 3) / 4, 256, 0, stream>>>(ei, E, Etot, lk1, dn1, h1, out1);
  bias_elu_kernel<9><<<(N * 512 + 255) / 256, 256, 0, stream>>>(out1, b1w, N * 512);

  // out2 aliases xw[N*64:], which gemm1 has now consumed — safe to zero here.
  hipMemsetAsync(out2, 0, (size_t)N * 64 * 4,  stream);

  // ---- layer 2 ----
  gemm2_kernel<<<(N + 15) / 16, 256, 0, stream>>>(out1, W2f, h2, N);
  attn_coef_kernel<1><<<(N + 3) / 4, 256, 0, stream>>>(h2, as2w, ad2w, as2, ad2, N);
  edge_max_kernel<1><<<(Etot + 255) / 256, 256, 0, stream>>>(ei, E, Etot, as2, ad2, m2, lk2);
  edge_expsum_kernel<1><<<(Etot + 255) / 256, 256, 0, stream>>>(ei, E, Etot, m2, lk2, dn2);
  edge_agg_kernel<1><<<(Etot + 3) / 4, 256, 0, stream>>>(ei, E, Etot, lk2, dn2, h2, out2);

  // ---- pool + head ----
  elu_pool_kernel<<<(N + 511) / 512, 256, 0, stream>>>(out2, b2w, batch, pooled, N);
  head_kernel<<<1, 512, 0, stream>>>(pooled, l1w, l1b, l2w, l2b, flag, (void*)d_out);
}

// Round 4
// 853.339 us; speedup vs baseline: 2.1621x; 2.1621x over previous
//
#include <hip/hip_runtime.h>
#include <hip/hip_bf16.h>

#define DEV static __device__ __forceinline__

constexpr int F1 = 128;   // input features
constexpr int H1 = 8;     // heads layer1
constexpr int C  = 64;    // channels per head
constexpr int B  = 64;    // graphs
constexpr int K  = 10;    // classes
constexpr float NEG = 0.2f;

DEV float b2f(__hip_bfloat16 x) { return __bfloat162float(x); }

// ---------- dtype detection + canonicalization ----------
__global__ void detect_kernel(const void* xraw, int* flag) {
  const __hip_bfloat16* xb = (const __hip_bfloat16*)xraw;
  int lane = threadIdx.x & 63;
  int bad = 0;
  for (int it = 0; it < 8; ++it) {
    int i = it * 64 + lane;
    float v = b2f(xb[2 * i]);
    if (!(fabsf(v) < 1e4f)) bad++;
  }
  for (int off = 32; off; off >>= 1) bad += __shfl_down(bad, off);
  if (lane == 0) *flag = (bad < 64) ? 1 : 0;   // 1 = bf16, 0 = f32
}

__global__ void convert_kernel(const void* __restrict__ raw,
                               float* __restrict__ dst, int n,
                               const int* __restrict__ flag) {
  int isbf = *flag;
  for (int i = blockIdx.x * blockDim.x + threadIdx.x; i < n;
       i += gridDim.x * blockDim.x) {
    dst[i] = isbf ? b2f(((const __hip_bfloat16*)raw)[i])
                  : ((const float*)raw)[i];
  }
}

// ---------- CSR construction (by destination) ----------
__global__ void deg_count_kernel(const int* __restrict__ ei, int E, int Etot,
                                 int* __restrict__ deg) {
  int e = blockIdx.x * blockDim.x + threadIdx.x;
  if (e >= Etot) return;
  int d = (e < E) ? ei[E + e] : e - E;
  atomicAdd(&deg[d], 1);
}

// per-block exclusive scan of deg -> local, block totals -> bsum
__global__ void scan_block_kernel(const int* __restrict__ deg,
                                  int* __restrict__ local,
                                  int* __restrict__ bsum, int N) {
  __shared__ int tmp[256];
  int t = threadIdx.x;
  int i = blockIdx.x * 256 + t;
  int v = (i < N) ? deg[i] : 0;
  tmp[t] = v;
  __syncthreads();
  for (int off = 1; off < 256; off <<= 1) {
    int u = (t >= off) ? tmp[t - off] : 0;
    __syncthreads();
    tmp[t] += u;
    __syncthreads();
  }
  if (i < N) local[i] = tmp[t] - v;          // exclusive
  if (t == 255) bsum[blockIdx.x] = tmp[255]; // block total
}

// single-block exclusive scan of block sums (nb <= 256)
__global__ void scan_sums_kernel(int* __restrict__ bsum, int nb) {
  __shared__ int tmp[256];
  int t = threadIdx.x;
  int v0 = (t < nb) ? bsum[t] : 0;
  tmp[t] = v0;
  __syncthreads();
  for (int off = 1; off < 256; off <<= 1) {
    int u = (t >= off) ? tmp[t - off] : 0;
    __syncthreads();
    tmp[t] += u;
    __syncthreads();
  }
  if (t < nb) bsum[t] = tmp[t] - v0;         // exclusive
}

__global__ void scan_add_kernel(const int* __restrict__ local,
                                const int* __restrict__ bsum,
                                int* __restrict__ rowptr,
                                int* __restrict__ cursor, int N, int Etot) {
  int i = blockIdx.x * 256 + threadIdx.x;
  if (i < N) {
    int r = local[i] + bsum[i >> 8];
    rowptr[i] = r;
    cursor[i] = r;
  }
  if (i == 0) rowptr[N] = Etot;
}

__global__ void csr_fill_kernel(const int* __restrict__ ei, int E, int Etot,
                                int* __restrict__ cursor, int* __restrict__ col) {
  int e = blockIdx.x * blockDim.x + threadIdx.x;
  if (e >= Etot) return;
  int s, d;
  if (e < E) { s = ei[e]; d = ei[E + e]; } else { s = d = e - E; }
  int pos = atomicAdd(&cursor[d], 1);
  col[pos] = s;
}

// ---------- layer GEMMs ----------
// h1[n,512] = x[n,0:128] @ W1[128,512]; 8 nodes per block.
__global__ void gemm1_kernel(const float* __restrict__ x,
                             const float* __restrict__ W,
                             float* __restrict__ out, int N) {
  __shared__ float xs[8][F1];
  int n0 = blockIdx.x * 8;
  int t = threadIdx.x;                 // 256
  for (int j = 0; j < 4; ++j) {
    int idx = t + j * 256;
    xs[idx >> 7][idx & 127] = x[(size_t)n0 * F1 + idx];
  }
  __syncthreads();
  float a0[8] = {}, a1[8] = {};
  for (int k = 0; k < F1; ++k) {
    float w0 = W[k * 512 + t];
    float w1 = W[k * 512 + t + 256];
#pragma unroll
    for (int j = 0; j < 8; ++j) {
      a0[j] += xs[j][k] * w0;
      a1[j] += xs[j][k] * w1;
    }
  }
#pragma unroll
  for (int j = 0; j < 8; ++j) {
    out[(size_t)(n0 + j) * 512 + t]       = a0[j];
    out[(size_t)(n0 + j) * 512 + t + 256] = a1[j];
  }
}

// h2[n,64] = x2[n,0:512] @ W2[512,64]; 4 nodes per wave, 16 per block.
__global__ void gemm2_kernel(const float* __restrict__ x2,
                             const float* __restrict__ W,
                             float* __restrict__ out, int N) {
  int wave = threadIdx.x >> 6, lane = threadIdx.x & 63;
  int n0 = (blockIdx.x * 4 + wave) * 4;
  if (n0 >= N) return;
  float acc[4] = {};
  for (int k = 0; k < 512; ++k) {
    float wv = W[k * 64 + lane];
#pragma unroll
    for (int j = 0; j < 4; ++j) acc[j] += x2[(size_t)(n0 + j) * 512 + k] * wv;
  }
#pragma unroll
  for (int j = 0; j < 4; ++j) out[(size_t)(n0 + j) * 64 + lane] = acc[j];
}

// ---------- attention coefficients ----------
template <int H>
__global__ void attn_coef_kernel(const float* __restrict__ h,
                                 const float* __restrict__ att_src,
                                 const float* __restrict__ att_dst,
                                 float* __restrict__ a_s, float* __restrict__ a_d,
                                 int N) {
  int wave = threadIdx.x >> 6, lane = threadIdx.x & 63;
  int n = blockIdx.x * 4 + wave;
  if (n >= N) return;
  for (int hh = 0; hh < H; ++hh) {
    float v  = h[(size_t)n * (H * 64) + hh * 64 + lane];
    float ps = v * att_src[hh * 64 + lane];
    float pd = v * att_dst[hh * 64 + lane];
    for (int off = 32; off; off >>= 1) {
      ps += __shfl_down(ps, off);
      pd += __shfl_down(pd, off);
    }
    if (lane == 0) {
      a_s[(size_t)n * H + hh] = ps;
      a_d[(size_t)n * H + hh] = pd;
    }
  }
}

// ---------- fused GAT aggregation: one wave per destination node ----------
// softmax(max, sum) via lane-parallel passes + shuffle reduce; gather pass
// accumulates in registers; fused bias + ELU; one coalesced store.
template <int H>
__global__ void gat_agg_kernel(const int* __restrict__ rowptr,
                               const int* __restrict__ col,
                               const float* __restrict__ a_s,
                               const float* __restrict__ a_d,
                               const float* __restrict__ hfeat,
                               const float* __restrict__ bias,
                               float* __restrict__ out, int N) {
  int wave = threadIdx.x >> 6, lane = threadIdx.x & 63;
  int d = blockIdx.x * 4 + wave;
  if (d >= N) return;
  int beg = rowptr[d], end = rowptr[d + 1];

  float adv[H], mx[H], sm[H];
#pragma unroll
  for (int h = 0; h < H; ++h) {
    adv[h] = a_d[(size_t)d * H + h];
    mx[h] = -1e30f;
    sm[h] = 0.f;
  }
  // pass A: lane-parallel max
  for (int i = beg + lane; i < end; i += 64) {
    int s = col[i];
#pragma unroll
    for (int h = 0; h < H; ++h) {
      float v = a_s[(size_t)s * H + h] + adv[h];
      v = v > 0.f ? v : NEG * v;
      mx[h] = fmaxf(mx[h], v);
    }
  }
#pragma unroll
  for (int h = 0; h < H; ++h)
    for (int off = 32; off; off >>= 1) mx[h] = fmaxf(mx[h], __shfl_xor(mx[h], off));
  // pass B: lane-parallel exp-sum
  for (int i = beg + lane; i < end; i += 64) {
    int s = col[i];
#pragma unroll
    for (int h = 0; h < H; ++h) {
      float v = a_s[(size_t)s * H + h] + adv[h];
      v = v > 0.f ? v : NEG * v;
      sm[h] += __expf(v - mx[h]);
    }
  }
#pragma unroll
  for (int h = 0; h < H; ++h) {
    for (int off = 32; off; off >>= 1) sm[h] += __shfl_xor(sm[h], off);
    sm[h] = 1.f / (sm[h] + 1e-16f);
  }
  // pass C: gather-accumulate (edge index uniform across wave)
  float acc[H] = {};
  for (int i = beg; i < end; ++i) {
    int s = col[i];   // wave-uniform
#pragma unroll
    for (int h = 0; h < H; ++h) {
      float v = a_s[(size_t)s * H + h] + adv[h];      // broadcast load
      v = v > 0.f ? v : NEG * v;
      float alpha = __expf(v - mx[h]) * sm[h];
      acc[h] += alpha * hfeat[(size_t)s * (H * 64) + h * 64 + lane];
    }
  }
#pragma unroll
  for (int h = 0; h < H; ++h) {
    float v = acc[h] + bias[h * 64 + lane];
    v = v > 0.f ? v : (__expf(v) - 1.f);              // ELU (both layers)
    out[(size_t)d * (H * 64) + h * 64 + lane] = v;
  }
}

// ---------- pooling (batch is sorted) ----------
__global__ void pool_kernel(const float* __restrict__ out2,
                            const int* __restrict__ batch,
                            float* __restrict__ pooled, int N) {
  int wave = threadIdx.x >> 6, lane = threadIdx.x & 63;
  int seg = blockIdx.x * 4 + wave;
  int start = seg * 128;
  if (start >= N) return;
  int end = min(start + 128, N);
  int cur = batch[start];
  float acc = 0.f;
  for (int n = start; n < end; ++n) {
    int bn = batch[n];
    if (bn != cur) {
      unsafeAtomicAdd(&pooled[cur * 64 + lane], acc);
      acc = 0.f; cur = bn;
    }
    acc += out2[(size_t)n * 64 + lane];
  }
  unsafeAtomicAdd(&pooled[cur * 64 + lane], acc);
}

// ---------- MLP head + log_softmax ----------
__global__ void head_kernel(const float* __restrict__ pooled,
                            const float* __restrict__ lin1_w,
                            const float* __restrict__ lin1_b,
                            const float* __restrict__ lin2_w,
                            const float* __restrict__ lin2_b,
                            const int* __restrict__ flag,
                            void* __restrict__ outv) {
  __shared__ float P[B * C];
  __shared__ float Z[B * C];
  __shared__ float L[B * K];
  int t = threadIdx.x;  // 512
  for (int i = t; i < B * C; i += 512) P[i] = pooled[i];
  __syncthreads();
  for (int i = t; i < B * C; i += 512) {
    int r = i >> 6, c = i & 63;
    float acc = lin1_b[c];
    for (int k = 0; k < C; ++k) acc += P[r * C + k] * lin1_w[k * C + c];
    Z[i] = acc > 0.f ? acc : (__expf(acc) - 1.f);
  }
  __syncthreads();
  for (int i = t; i < B * K; i += 512) {
    int r = i / K, c = i - r * K;
    float acc = lin2_b[c];
    for (int k = 0; k < C; ++k) acc += Z[r * C + k] * lin2_w[k * K + c];
    L[i] = acc;
  }
  __syncthreads();
  if (t < B) {
    float mx = -1e30f;
    for (int c = 0; c < K; ++c) mx = fmaxf(mx, L[t * K + c]);
    float s = 0.f;
    for (int c = 0; c < K; ++c) s += __expf(L[t * K + c] - mx);
    float lse = mx + __logf(s);
    int isbf = *flag;
    for (int c = 0; c < K; ++c) {
      float val = L[t * K + c] - lse;
      if (isbf) ((__hip_bfloat16*)outv)[t * K + c] = __float2bfloat16(val);
      else      ((float*)outv)[t * K + c] = val;
    }
  }
}

extern "C" void kernel_launch(void* const* d_in, const int* in_sizes, int n_in,
                              void* d_out, int out_size, void* d_ws, size_t ws_size,
                              hipStream_t stream) {
  const void* x_raw = d_in[0];
  const int*  ei    = (const int*)d_in[1];
  const int*  batch = (const int*)d_in[2];

  const int N    = in_sizes[2];
  const int E    = in_sizes[1] / 2;
  const int Etot = E + N;
  const int nb   = (N + 255) / 256;   // scan blocks (<=256)

  int*   flag = (int*)d_ws;
  float* ws   = (float*)d_ws;
  size_t off  = 16;

  float* xw   = ws + off; off += (size_t)N * F1;
  float* W1f  = ws + off; off += 128 * 512;
  float* as1w = ws + off; off += 512;
  float* ad1w = ws + off; off += 512;
  float* b1w  = ws + off; off += 512;
  float* W2f  = ws + off; off += 512 * 64;
  float* as2w = ws + off; off += 64;
  float* ad2w = ws + off; off += 64;
  float* b2w  = ws + off; off += 64;
  float* l1w  = ws + off; off += 64 * 64;
  float* l1b  = ws + off; off += 64;
  float* l2w  = ws + off; off += 640;
  float* l2b  = ws + off; off += 16;

  float* h1   = ws + off; off += (size_t)N * 512;
  float* out1 = ws + off; off += (size_t)N * 512;
  float* as1  = ws + off; off += (size_t)N * H1;
  float* ad1  = ws + off; off += (size_t)N * H1;
  float* as2  = ws + off; off += (size_t)N;
  float* ad2  = ws + off; off += (size_t)N;
  float* pooled = ws + off; off += (size_t)B * C;

  // int region (CSR)
  int* ibase  = (int*)(ws + off);
  int* deg    = ibase;                 ibase += N;
  int* cursor = ibase;                 ibase += N;
  int* rowptr = ibase;                 ibase += N + 1;
  int* locals = ibase;                 ibase += N;
  int* bsum   = ibase;                 ibase += 256;
  int* col    = ibase;                 ibase += Etot;

  // layer-2 feature buffers alias xw (x dead after gemm1; both fully written
  // by their producer kernels, stream-ordered after gemm1)
  float* h2   = xw;
  float* out2 = xw + (size_t)N * 64;

  // ---- dtype detect + canonicalize ----
  detect_kernel<<<1, 64, 0, stream>>>(x_raw, flag);
  auto conv = [&](const void* raw, float* dst, int n) {
    int grid = (n + 255) / 256; if (grid > 8192) grid = 8192;
    convert_kernel<<<grid, 256, 0, stream>>>(raw, dst, n, flag);
  };
  conv(d_in[0],  xw,   in_sizes[0]);
  conv(d_in[3],  W1f,  in_sizes[3]);
  conv(d_in[4],  as1w, in_sizes[4]);
  conv(d_in[5],  ad1w, in_sizes[5]);
  conv(d_in[6],  b1w,  in_sizes[6]);
  conv(d_in[7],  W2f,  in_sizes[7]);
  conv(d_in[8],  as2w, in_sizes[8]);
  conv(d_in[9],  ad2w, in_sizes[9]);
  conv(d_in[10], b2w,  in_sizes[10]);
  conv(d_in[11], l1w,  in_sizes[11]);
  conv(d_in[12], l1b,  in_sizes[12]);
  conv(d_in[13], l2w,  in_sizes[13]);
  conv(d_in[14], l2b,  in_sizes[14]);

  // ---- CSR build ----
  hipMemsetAsync(deg, 0, (size_t)N * 4, stream);
  hipMemsetAsync(pooled, 0, (size_t)B * C * 4, stream);
  deg_count_kernel<<<(Etot + 255) / 256, 256, 0, stream>>>(ei, E, Etot, deg);
  scan_block_kernel<<<nb, 256, 0, stream>>>(deg, locals, bsum, N);
  scan_sums_kernel<<<1, 256, 0, stream>>>(bsum, nb);
  scan_add_kernel<<<nb, 256, 0, stream>>>(locals, bsum, rowptr, cursor, N, Etot);
  csr_fill_kernel<<<(Etot + 255) / 256, 256, 0, stream>>>(ei, E, Etot, cursor, col);

  // ---- layer 1 ----
  gemm1_kernel<<<N / 8, 256, 0, stream>>>(xw, W1f, h1, N);
  attn_coef_kernel<H1><<<(N + 3) / 4, 256, 0, stream>>>(h1, as1w, ad1w, as1, ad1, N);
  gat_agg_kernel<H1><<<(N + 3) / 4, 256, 0, stream>>>(rowptr, col, as1, ad1, h1, b1w, out1, N);

  // ---- layer 2 ----
  gemm2_kernel<<<(N + 15) / 16, 256, 0, stream>>>(out1, W2f, h2, N);
  attn_coef_kernel<1><<<(N + 3) / 4, 256, 0, stream>>>(h2, as2w, ad2w, as2, ad2, N);
  gat_agg_kernel<1><<<(N + 3) / 4, 256, 0, stream>>>(rowptr, col, as2, ad2, h2, b2w, out2, N);

  // ---- pool + head ----
  pool_kernel<<<(N + 511) / 512, 256, 0, stream>>>(out2, batch, pooled, N);
  head_kernel<<<1, 512, 0, stream>>>(pooled, l1w, l1b, l2w, l2b, flag, (void*)d_out);
}

// Round 5
// 592.532 us; speedup vs baseline: 3.1138x; 1.4402x over previous
//
#include <hip/hip_runtime.h>
#include <hip/hip_bf16.h>

#define DEV static __device__ __forceinline__

constexpr int F1 = 128;   // input features
constexpr int H1 = 8;     // heads layer1
constexpr int C  = 64;    // channels per head
constexpr int B  = 64;    // graphs
constexpr int K  = 10;    // classes
constexpr float NEG = 0.2f;

DEV float b2f(__hip_bfloat16 x) { return __bfloat162float(x); }
DEV float elu1(float v) { return v > 0.f ? v : (__expf(v) - 1.f); }

// ---------- dtype detection + canonicalization ----------
__global__ void detect_kernel(const void* xraw, int* flag) {
  const __hip_bfloat16* xb = (const __hip_bfloat16*)xraw;
  int lane = threadIdx.x & 63;
  int bad = 0;
  for (int it = 0; it < 8; ++it) {
    int i = it * 64 + lane;
    float v = b2f(xb[2 * i]);
    if (!(fabsf(v) < 1e4f)) bad++;
  }
  for (int off = 32; off; off >>= 1) bad += __shfl_down(bad, off);
  if (lane == 0) *flag = (bad < 64) ? 1 : 0;   // 1 = bf16, 0 = f32
}

__global__ void convert_kernel(const void* __restrict__ raw,
                               float* __restrict__ dst, int n,
                               const int* __restrict__ flag) {
  int isbf = *flag;
  for (int i = blockIdx.x * blockDim.x + threadIdx.x; i < n;
       i += gridDim.x * blockDim.x) {
    dst[i] = isbf ? b2f(((const __hip_bfloat16*)raw)[i])
                  : ((const float*)raw)[i];
  }
}

// All 12 small weight tensors in ONE dispatch. Compile-time sizes/offsets.
#define CVT(p, i) (isbf ? b2f(((const __hip_bfloat16*)(p))[i]) : ((const float*)(p))[i])
__global__ void conv_wts_kernel(const void* s0, const void* s1, const void* s2,
                                const void* s3, const void* s4, const void* s5,
                                const void* s6, const void* s7, const void* s8,
                                const void* s9, const void* s10, const void* s11,
                                float* __restrict__ dst,
                                const int* __restrict__ flag) {
  int isbf = *flag;
  int gid = blockIdx.x * 256 + threadIdx.x;
  int stride = gridDim.x * 256;
  for (int i = gid; i < 65536; i += stride) dst[0      + i] = CVT(s0, i);  // W1
  for (int i = gid; i < 512;   i += stride) dst[65536  + i] = CVT(s1, i);  // att_src1
  for (int i = gid; i < 512;   i += stride) dst[66048  + i] = CVT(s2, i);  // att_dst1
  for (int i = gid; i < 512;   i += stride) dst[66560  + i] = CVT(s3, i);  // b1
  for (int i = gid; i < 32768; i += stride) dst[67072  + i] = CVT(s4, i);  // W2
  for (int i = gid; i < 64;    i += stride) dst[99840  + i] = CVT(s5, i);  // att_src2
  for (int i = gid; i < 64;    i += stride) dst[99904  + i] = CVT(s6, i);  // att_dst2
  for (int i = gid; i < 64;    i += stride) dst[99968  + i] = CVT(s7, i);  // b2
  for (int i = gid; i < 4096;  i += stride) dst[100032 + i] = CVT(s8, i);  // lin1_w
  for (int i = gid; i < 64;    i += stride) dst[104128 + i] = CVT(s9, i);  // lin1_b
  for (int i = gid; i < 640;   i += stride) dst[104192 + i] = CVT(s10, i); // lin2_w
  for (int i = gid; i < 10;    i += stride) dst[104832 + i] = CVT(s11, i); // lin2_b
}

// ---------- CSR construction (by destination) ----------
__global__ void deg_count_kernel(const int* __restrict__ ei, int E, int Etot,
                                 int* __restrict__ deg) {
  int e = blockIdx.x * blockDim.x + threadIdx.x;
  if (e >= Etot) return;
  int d = (e < E) ? ei[E + e] : e - E;
  atomicAdd(&deg[d], 1);
}

__global__ void scan_block_kernel(const int* __restrict__ deg,
                                  int* __restrict__ local,
                                  int* __restrict__ bsum, int N) {
  __shared__ int tmp[256];
  int t = threadIdx.x;
  int i = blockIdx.x * 256 + t;
  int v = (i < N) ? deg[i] : 0;
  tmp[t] = v;
  __syncthreads();
  for (int off = 1; off < 256; off <<= 1) {
    int u = (t >= off) ? tmp[t - off] : 0;
    __syncthreads();
    tmp[t] += u;
    __syncthreads();
  }
  if (i < N) local[i] = tmp[t] - v;
  if (t == 255) bsum[blockIdx.x] = tmp[255];
}

__global__ void scan_sums_kernel(int* __restrict__ bsum, int nb) {
  __shared__ int tmp[256];
  int t = threadIdx.x;
  int v0 = (t < nb) ? bsum[t] : 0;
  tmp[t] = v0;
  __syncthreads();
  for (int off = 1; off < 256; off <<= 1) {
    int u = (t >= off) ? tmp[t - off] : 0;
    __syncthreads();
    tmp[t] += u;
    __syncthreads();
  }
  if (t < nb) bsum[t] = tmp[t] - v0;
}

__global__ void scan_add_kernel(const int* __restrict__ local,
                                const int* __restrict__ bsum,
                                int* __restrict__ rowptr,
                                int* __restrict__ cursor, int N, int Etot) {
  int i = blockIdx.x * 256 + threadIdx.x;
  if (i < N) {
    int r = local[i] + bsum[i >> 8];
    rowptr[i] = r;
    cursor[i] = r;
  }
  if (i == 0) rowptr[N] = Etot;
}

__global__ void csr_fill_kernel(const int* __restrict__ ei, int E, int Etot,
                                int* __restrict__ cursor, int* __restrict__ col) {
  int e = blockIdx.x * blockDim.x + threadIdx.x;
  if (e >= Etot) return;
  int s, d;
  if (e < E) { s = ei[e]; d = ei[E + e]; } else { s = d = e - E; }
  int pos = atomicAdd(&cursor[d], 1);
  col[pos] = s;
}

// ---------- tiled f32 SGEMM + fused attention-coefficient epilogue ----------
// C[m,n] = sum_k A[m,k]*Bm[k,n]; A: M x Kd row-major, Bm: Kd x Ncols row-major.
// Block: 64x64 C tile, 256 threads, 4x4 micro-tile. blockIdx.y = column tile
// = head index; epilogue computes a_s[m,h], a_d[m,h] via 16-lane reduction.
template <int H>
__global__ void sgemm_attn_kernel(const float* __restrict__ A,
                                  const float* __restrict__ Bm,
                                  const float* __restrict__ att_src,
                                  const float* __restrict__ att_dst,
                                  float* __restrict__ Cm,
                                  float* __restrict__ a_s,
                                  float* __restrict__ a_d,
                                  int M, int Kd, int Ncols) {
  __shared__ __align__(16) float As[16][68];
  __shared__ __align__(16) float Bs[16][68];
  int t = threadIdx.x;                 // 256
  int tx = t & 15, ty = t >> 4;
  int mt = blockIdx.x * 64;
  int ct = blockIdx.y;                 // head / column tile
  int n0 = ct * 64;

  int am = t >> 2;                     // 0..63 (row within tile)
  int ak = (t & 3) * 4;                // 0,4,8,12
  int bk = t >> 4;                     // 0..15
  int bn = (t & 15) * 4;               // 0..60

  int mg = mt + am; if (mg >= M) mg = M - 1;   // clamp (guard stores later)
  const float* Arow = A + (size_t)mg * Kd;

  float acc[4][4] = {};
  for (int kc = 0; kc < Kd; kc += 16) {
    float4 av = *(const float4*)&Arow[kc + ak];
    As[ak + 0][am] = av.x;
    As[ak + 1][am] = av.y;
    As[ak + 2][am] = av.z;
    As[ak + 3][am] = av.w;
    *(float4*)&Bs[bk][bn] = *(const float4*)&Bm[(size_t)(kc + bk) * Ncols + n0 + bn];
    __syncthreads();
#pragma unroll
    for (int k = 0; k < 16; ++k) {
      float4 a4 = *(const float4*)&As[k][ty * 4];
      float4 b4 = *(const float4*)&Bs[k][tx * 4];
      float aa[4] = {a4.x, a4.y, a4.z, a4.w};
      float bb[4] = {b4.x, b4.y, b4.z, b4.w};
#pragma unroll
      for (int i = 0; i < 4; ++i)
#pragma unroll
        for (int j = 0; j < 4; ++j) acc[i][j] += aa[i] * bb[j];
    }
    __syncthreads();
  }

  float4 asv = *(const float4*)&att_src[n0 + tx * 4];
  float4 adv = *(const float4*)&att_dst[n0 + tx * 4];
#pragma unroll
  for (int i = 0; i < 4; ++i) {
    int m = mt + ty * 4 + i;
    bool valid = (m < M);
    if (valid)
      *(float4*)&Cm[(size_t)m * Ncols + n0 + tx * 4] =
          make_float4(acc[i][0], acc[i][1], acc[i][2], acc[i][3]);
    float ps = acc[i][0] * asv.x + acc[i][1] * asv.y +
               acc[i][2] * asv.z + acc[i][3] * asv.w;
    float pd = acc[i][0] * adv.x + acc[i][1] * adv.y +
               acc[i][2] * adv.z + acc[i][3] * adv.w;
#pragma unroll
    for (int off = 1; off < 16; off <<= 1) {
      ps += __shfl_xor(ps, off);
      pd += __shfl_xor(pd, off);
    }
    if (tx == 0 && valid) {
      a_s[(size_t)m * H + ct] = ps;
      a_d[(size_t)m * H + ct] = pd;
    }
  }
}

// ---------- fused GAT aggregation ----------
// H=8 vectorized: one wave per dst; lane covers 2 float4 quads (heads h0,h0+4).
__global__ void gat_agg8_kernel(const int* __restrict__ rowptr,
                                const int* __restrict__ col,
                                const float* __restrict__ a_s,
                                const float* __restrict__ a_d,
                                const float* __restrict__ hfeat,
                                const float* __restrict__ bias,
                                float* __restrict__ out, int N) {
  int wave = threadIdx.x >> 6, lane = threadIdx.x & 63;
  int d = blockIdx.x * 4 + wave;
  if (d >= N) return;
  int beg = rowptr[d], end = rowptr[d + 1];

  float adv[8], mx[8], sm[8];
#pragma unroll
  for (int h = 0; h < 8; ++h) {
    adv[h] = a_d[(size_t)d * 8 + h];
    mx[h] = -1e30f;
    sm[h] = 0.f;
  }
  for (int i = beg + lane; i < end; i += 64) {
    int s = col[i];
#pragma unroll
    for (int h = 0; h < 8; ++h) {
      float v = a_s[(size_t)s * 8 + h] + adv[h];
      v = v > 0.f ? v : NEG * v;
      mx[h] = fmaxf(mx[h], v);
    }
  }
#pragma unroll
  for (int h = 0; h < 8; ++h)
    for (int off = 32; off; off >>= 1) mx[h] = fmaxf(mx[h], __shfl_xor(mx[h], off));
  for (int i = beg + lane; i < end; i += 64) {
    int s = col[i];
#pragma unroll
    for (int h = 0; h < 8; ++h) {
      float v = a_s[(size_t)s * 8 + h] + adv[h];
      v = v > 0.f ? v : NEG * v;
      sm[h] += __expf(v - mx[h]);
    }
  }
#pragma unroll
  for (int h = 0; h < 8; ++h) {
    for (int off = 32; off; off >>= 1) sm[h] += __shfl_xor(sm[h], off);
    sm[h] = 1.f / (sm[h] + 1e-16f);
  }

  int h0 = lane >> 4;                       // head of quad lane; h1 = h0+4
#define SEL4(a0, a1, a2, a3) (h0 == 0 ? (a0) : h0 == 1 ? (a1) : h0 == 2 ? (a2) : (a3))
  float mxa = SEL4(mx[0], mx[1], mx[2], mx[3]);
  float mxb = SEL4(mx[4], mx[5], mx[6], mx[7]);
  float sma = SEL4(sm[0], sm[1], sm[2], sm[3]);
  float smb = SEL4(sm[4], sm[5], sm[6], sm[7]);
  float ada = SEL4(adv[0], adv[1], adv[2], adv[3]);
  float adb = SEL4(adv[4], adv[5], adv[6], adv[7]);
#undef SEL4

  const float4* hf4 = (const float4*)hfeat;  // 128 quads per node row
  float4 acca = {0.f, 0.f, 0.f, 0.f}, accb = {0.f, 0.f, 0.f, 0.f};
  int h1 = h0 + 4;
  for (int i = beg; i < end; ++i) {
    int s = col[i];                          // wave-uniform
    float ea = a_s[(size_t)s * 8 + h0] + ada;
    ea = ea > 0.f ? ea : NEG * ea;
    float aa = __expf(ea - mxa) * sma;
    float eb = a_s[(size_t)s * 8 + h1] + adb;
    eb = eb > 0.f ? eb : NEG * eb;
    float ab = __expf(eb - mxb) * smb;
    float4 fa = hf4[(size_t)s * 128 + lane];
    float4 fb = hf4[(size_t)s * 128 + 64 + lane];
    acca.x += aa * fa.x; acca.y += aa * fa.y; acca.z += aa * fa.z; acca.w += aa * fa.w;
    accb.x += ab * fb.x; accb.y += ab * fb.y; accb.z += ab * fb.z; accb.w += ab * fb.w;
  }
  const float4* b4 = (const float4*)bias;
  float4 ba = b4[lane], bbv = b4[64 + lane];
  float4 oa = make_float4(elu1(acca.x + ba.x), elu1(acca.y + ba.y),
                          elu1(acca.z + ba.z), elu1(acca.w + ba.w));
  float4 ob = make_float4(elu1(accb.x + bbv.x), elu1(accb.y + bbv.y),
                          elu1(accb.z + bbv.z), elu1(accb.w + bbv.w));
  float4* o4 = (float4*)out;
  o4[(size_t)d * 128 + lane]      = oa;
  o4[(size_t)d * 128 + 64 + lane] = ob;
}

// H=1: one wave per dst, lane = channel.
__global__ void gat_agg1_kernel(const int* __restrict__ rowptr,
                                const int* __restrict__ col,
                                const float* __restrict__ a_s,
                                const float* __restrict__ a_d,
                                const float* __restrict__ hfeat,
                                const float* __restrict__ bias,
                                float* __restrict__ out, int N) {
  int wave = threadIdx.x >> 6, lane = threadIdx.x & 63;
  int d = blockIdx.x * 4 + wave;
  if (d >= N) return;
  int beg = rowptr[d], end = rowptr[d + 1];
  float adv = a_d[d];
  float mx = -1e30f, sm = 0.f;
  for (int i = beg + lane; i < end; i += 64) {
    float v = a_s[col[i]] + adv;
    v = v > 0.f ? v : NEG * v;
    mx = fmaxf(mx, v);
  }
  for (int off = 32; off; off >>= 1) mx = fmaxf(mx, __shfl_xor(mx, off));
  for (int i = beg + lane; i < end; i += 64) {
    float v = a_s[col[i]] + adv;
    v = v > 0.f ? v : NEG * v;
    sm += __expf(v - mx);
  }
  for (int off = 32; off; off >>= 1) sm += __shfl_xor(sm, off);
  float sminv = 1.f / (sm + 1e-16f);
  float acc = 0.f;
  for (int i = beg; i < end; ++i) {
    int s = col[i];
    float v = a_s[s] + adv;
    v = v > 0.f ? v : NEG * v;
    float alpha = __expf(v - mx) * sminv;
    acc += alpha * hfeat[(size_t)s * 64 + lane];
  }
  out[(size_t)d * 64 + lane] = elu1(acc + bias[lane]);
}

// ---------- pooling (batch sorted) ----------
__global__ void pool_kernel(const float* __restrict__ out2,
                            const int* __restrict__ batch,
                            float* __restrict__ pooled, int N) {
  int wave = threadIdx.x >> 6, lane = threadIdx.x & 63;
  int seg = blockIdx.x * 4 + wave;
  int start = seg * 128;
  if (start >= N) return;
  int end = min(start + 128, N);
  int cur = batch[start];
  float acc = 0.f;
  for (int n = start; n < end; ++n) {
    int bn = batch[n];
    if (bn != cur) {
      unsafeAtomicAdd(&pooled[cur * 64 + lane], acc);
      acc = 0.f; cur = bn;
    }
    acc += out2[(size_t)n * 64 + lane];
  }
  unsafeAtomicAdd(&pooled[cur * 64 + lane], acc);
}

// ---------- MLP head + log_softmax ----------
__global__ void head_kernel(const float* __restrict__ pooled,
                            const float* __restrict__ lin1_w,
                            const float* __restrict__ lin1_b,
                            const float* __restrict__ lin2_w,
                            const float* __restrict__ lin2_b,
                            const int* __restrict__ flag,
                            void* __restrict__ outv) {
  __shared__ float P[B * C];
  __shared__ float Z[B * C];
  __shared__ float L[B * K];
  int t = threadIdx.x;  // 512
  for (int i = t; i < B * C; i += 512) P[i] = pooled[i];
  __syncthreads();
  for (int i = t; i < B * C; i += 512) {
    int r = i >> 6, c = i & 63;
    float acc = lin1_b[c];
    for (int k = 0; k < C; ++k) acc += P[r * C + k] * lin1_w[k * C + c];
    Z[i] = elu1(acc);
  }
  __syncthreads();
  for (int i = t; i < B * K; i += 512) {
    int r = i / K, c = i - r * K;
    float acc = lin2_b[c];
    for (int k = 0; k < C; ++k) acc += Z[r * C + k] * lin2_w[k * K + c];
    L[i] = acc;
  }
  __syncthreads();
  if (t < B) {
    float mx = -1e30f;
    for (int c = 0; c < K; ++c) mx = fmaxf(mx, L[t * K + c]);
    float s = 0.f;
    for (int c = 0; c < K; ++c) s += __expf(L[t * K + c] - mx);
    float lse = mx + __logf(s);
    int isbf = *flag;
    for (int c = 0; c < K; ++c) {
      float val = L[t * K + c] - lse;
      if (isbf) ((__hip_bfloat16*)outv)[t * K + c] = __float2bfloat16(val);
      else      ((float*)outv)[t * K + c] = val;
    }
  }
}

extern "C" void kernel_launch(void* const* d_in, const int* in_sizes, int n_in,
                              void* d_out, int out_size, void* d_ws, size_t ws_size,
                              hipStream_t stream) {
  const void* x_raw = d_in[0];
  const int*  ei    = (const int*)d_in[1];
  const int*  batch = (const int*)d_in[2];

  const int N    = in_sizes[2];
  const int E    = in_sizes[1] / 2;
  const int Etot = E + N;
  const int nb   = (N + 255) / 256;

  int*   flag = (int*)d_ws;
  float* ws   = (float*)d_ws;
  size_t off  = 16;

  float* xw  = ws + off; off += (size_t)N * F1;
  float* wts = ws + off; off += 104848;          // all weights, fixed offsets
  float* W1f  = wts + 0;
  float* as1w = wts + 65536;
  float* ad1w = wts + 66048;
  float* b1w  = wts + 66560;
  float* W2f  = wts + 67072;
  float* as2w = wts + 99840;
  float* ad2w = wts + 99904;
  float* b2w  = wts + 99968;
  float* l1w  = wts + 100032;
  float* l1b  = wts + 104128;
  float* l2w  = wts + 104192;
  float* l2b  = wts + 104832;

  float* h1   = ws + off; off += (size_t)N * 512;
  float* out1 = ws + off; off += (size_t)N * 512;
  float* as1  = ws + off; off += (size_t)N * H1;
  float* ad1  = ws + off; off += (size_t)N * H1;
  float* as2  = ws + off; off += (size_t)N;
  float* ad2  = ws + off; off += (size_t)N;
  float* pooled = ws + off; off += (size_t)B * C;

  int* ibase  = (int*)(ws + off);
  int* deg    = ibase;                 ibase += N;
  int* cursor = ibase;                 ibase += N;
  int* rowptr = ibase;                 ibase += N + 1;
  int* locals = ibase;                 ibase += N;
  int* bsum   = ibase;                 ibase += 256;
  int* col    = ibase;                 ibase += Etot;

  // layer-2 feature buffers alias xw (x dead after sgemm layer 1)
  float* h2   = xw;
  float* out2 = xw + (size_t)N * 64;

  // ---- dtype detect + canonicalize ----
  detect_kernel<<<1, 64, 0, stream>>>(x_raw, flag);
  {
    int n = in_sizes[0];
    int grid = (n + 255) / 256; if (grid > 8192) grid = 8192;
    convert_kernel<<<grid, 256, 0, stream>>>(d_in[0], xw, n, flag);
  }
  conv_wts_kernel<<<256, 256, 0, stream>>>(d_in[3], d_in[4], d_in[5], d_in[6],
                                           d_in[7], d_in[8], d_in[9], d_in[10],
                                           d_in[11], d_in[12], d_in[13], d_in[14],
                                           wts, flag);

  // ---- CSR build ----
  hipMemsetAsync(deg, 0, (size_t)N * 4, stream);
  hipMemsetAsync(pooled, 0, (size_t)B * C * 4, stream);
  deg_count_kernel<<<(Etot + 255) / 256, 256, 0, stream>>>(ei, E, Etot, deg);
  scan_block_kernel<<<nb, 256, 0, stream>>>(deg, locals, bsum, N);
  scan_sums_kernel<<<1, 256, 0, stream>>>(bsum, nb);
  scan_add_kernel<<<nb, 256, 0, stream>>>(locals, bsum, rowptr, cursor, N, Etot);
  csr_fill_kernel<<<(Etot + 255) / 256, 256, 0, stream>>>(ei, E, Etot, cursor, col);

  // ---- layer 1: h1 = xw @ W1 (+ attn coefs fused) ----
  {
    dim3 grid((N + 63) / 64, 8);
    sgemm_attn_kernel<H1><<<grid, 256, 0, stream>>>(xw, W1f, as1w, ad1w,
                                                    h1, as1, ad1, N, F1, 512);
  }
  gat_agg8_kernel<<<(N + 3) / 4, 256, 0, stream>>>(rowptr, col, as1, ad1, h1, b1w, out1, N);

  // ---- layer 2: h2 = out1 @ W2 (+ attn coefs fused) ----
  {
    dim3 grid((N + 63) / 64, 1);
    sgemm_attn_kernel<1><<<grid, 256, 0, stream>>>(out1, W2f, as2w, ad2w,
                                                   h2, as2, ad2, N, 512, 64);
  }
  gat_agg1_kernel<<<(N + 3) / 4, 256, 0, stream>>>(rowptr, col, as2, ad2, h2, b2w, out2, N);

  // ---- pool + head ----
  pool_kernel<<<(N + 511) / 512, 256, 0, stream>>>(out2, batch, pooled, N);
  head_kernel<<<1, 512, 0, stream>>>(pooled, l1w, l1b, l2w, l2b, flag, (void*)d_out);
}

// Round 6
// 537.112 us; speedup vs baseline: 3.4351x; 1.1032x over previous
//
#include <hip/hip_runtime.h>
#include <hip/hip_bf16.h>

#define DEV static __device__ __forceinline__

constexpr int F1 = 128;   // input features
constexpr int H1 = 8;     // heads layer1
constexpr int C  = 64;    // channels per head
constexpr int B  = 64;    // graphs
constexpr int K  = 10;    // classes
constexpr float NEG = 0.2f;

DEV float b2f(__hip_bfloat16 x) { return __bfloat162float(x); }
DEV float elu1(float v) { return v > 0.f ? v : (__expf(v) - 1.f); }
DEV unsigned short f2bbits(float f) {
  __hip_bfloat16 b = __float2bfloat16(f);
  return *(unsigned short*)&b;
}
DEV float blo(unsigned u) { return __uint_as_float(u << 16); }
DEV float bhi(unsigned u) { return __uint_as_float(u & 0xffff0000u); }

// ---------- dtype detection + canonicalization ----------
__global__ void detect_kernel(const void* xraw, int* flag) {
  const __hip_bfloat16* xb = (const __hip_bfloat16*)xraw;
  int lane = threadIdx.x & 63;
  int bad = 0;
  for (int it = 0; it < 8; ++it) {
    int i = it * 64 + lane;
    float v = b2f(xb[2 * i]);
    if (!(fabsf(v) < 1e4f)) bad++;
  }
  for (int off = 32; off; off >>= 1) bad += __shfl_down(bad, off);
  if (lane == 0) *flag = (bad < 64) ? 1 : 0;   // 1 = bf16, 0 = f32
}

__global__ void convert_kernel(const void* __restrict__ raw,
                               float* __restrict__ dst, int n,
                               const int* __restrict__ flag) {
  int isbf = *flag;
  for (int i = blockIdx.x * blockDim.x + threadIdx.x; i < n;
       i += gridDim.x * blockDim.x) {
    dst[i] = isbf ? b2f(((const __hip_bfloat16*)raw)[i])
                  : ((const float*)raw)[i];
  }
}

// All 12 small weight tensors in ONE dispatch.
#define CVT(p, i) (isbf ? b2f(((const __hip_bfloat16*)(p))[i]) : ((const float*)(p))[i])
__global__ void conv_wts_kernel(const void* s0, const void* s1, const void* s2,
                                const void* s3, const void* s4, const void* s5,
                                const void* s6, const void* s7, const void* s8,
                                const void* s9, const void* s10, const void* s11,
                                float* __restrict__ dst,
                                const int* __restrict__ flag) {
  int isbf = *flag;
  int gid = blockIdx.x * 256 + threadIdx.x;
  int stride = gridDim.x * 256;
  for (int i = gid; i < 65536; i += stride) dst[0      + i] = CVT(s0, i);  // W1
  for (int i = gid; i < 512;   i += stride) dst[65536  + i] = CVT(s1, i);  // att_src1
  for (int i = gid; i < 512;   i += stride) dst[66048  + i] = CVT(s2, i);  // att_dst1
  for (int i = gid; i < 512;   i += stride) dst[66560  + i] = CVT(s3, i);  // b1
  for (int i = gid; i < 32768; i += stride) dst[67072  + i] = CVT(s4, i);  // W2
  for (int i = gid; i < 64;    i += stride) dst[99840  + i] = CVT(s5, i);  // att_src2
  for (int i = gid; i < 64;    i += stride) dst[99904  + i] = CVT(s6, i);  // att_dst2
  for (int i = gid; i < 64;    i += stride) dst[99968  + i] = CVT(s7, i);  // b2
  for (int i = gid; i < 4096;  i += stride) dst[100032 + i] = CVT(s8, i);  // lin1_w
  for (int i = gid; i < 64;    i += stride) dst[104128 + i] = CVT(s9, i);  // lin1_b
  for (int i = gid; i < 640;   i += stride) dst[104192 + i] = CVT(s10, i); // lin2_w
  for (int i = gid; i < 10;    i += stride) dst[104832 + i] = CVT(s11, i); // lin2_b
}

// ---------- CSR construction (by destination) ----------
__global__ void deg_count_kernel(const int* __restrict__ ei, int E, int Etot,
                                 int* __restrict__ deg) {
  int e = blockIdx.x * blockDim.x + threadIdx.x;
  if (e >= Etot) return;
  int d = (e < E) ? ei[E + e] : e - E;
  atomicAdd(&deg[d], 1);
}

__global__ void scan_block_kernel(const int* __restrict__ deg,
                                  int* __restrict__ local,
                                  int* __restrict__ bsum, int N) {
  __shared__ int tmp[256];
  int t = threadIdx.x;
  int i = blockIdx.x * 256 + t;
  int v = (i < N) ? deg[i] : 0;
  tmp[t] = v;
  __syncthreads();
  for (int off = 1; off < 256; off <<= 1) {
    int u = (t >= off) ? tmp[t - off] : 0;
    __syncthreads();
    tmp[t] += u;
    __syncthreads();
  }
  if (i < N) local[i] = tmp[t] - v;
  if (t == 255) bsum[blockIdx.x] = tmp[255];
}

__global__ void scan_sums_kernel(int* __restrict__ bsum, int nb) {
  __shared__ int tmp[256];
  int t = threadIdx.x;
  int v0 = (t < nb) ? bsum[t] : 0;
  tmp[t] = v0;
  __syncthreads();
  for (int off = 1; off < 256; off <<= 1) {
    int u = (t >= off) ? tmp[t - off] : 0;
    __syncthreads();
    tmp[t] += u;
    __syncthreads();
  }
  if (t < nb) bsum[t] = tmp[t] - v0;
}

__global__ void scan_add_kernel(const int* __restrict__ local,
                                const int* __restrict__ bsum,
                                int* __restrict__ rowptr,
                                int* __restrict__ cursor, int N, int Etot) {
  int i = blockIdx.x * 256 + threadIdx.x;
  if (i < N) {
    int r = local[i] + bsum[i >> 8];
    rowptr[i] = r;
    cursor[i] = r;
  }
  if (i == 0) rowptr[N] = Etot;
}

__global__ void csr_fill_kernel(const int* __restrict__ ei, int E, int Etot,
                                int* __restrict__ cursor, int* __restrict__ col) {
  int e = blockIdx.x * blockDim.x + threadIdx.x;
  if (e >= Etot) return;
  int s, d;
  if (e < E) { s = ei[e]; d = ei[E + e]; } else { s = d = e - E; }
  int pos = atomicAdd(&cursor[d], 1);
  col[pos] = s;
}

// ---------- tiled f32 SGEMM + fused attention-coefficient epilogue ----------
// OUTBF: store C as bf16 (feature gather consumer) while attn coefs stay f32.
template <int H, bool OUTBF>
__global__ void sgemm_attn_kernel(const float* __restrict__ A,
                                  const float* __restrict__ Bm,
                                  const float* __restrict__ att_src,
                                  const float* __restrict__ att_dst,
                                  void* __restrict__ Cm,
                                  float* __restrict__ a_s,
                                  float* __restrict__ a_d,
                                  int M, int Kd, int Ncols) {
  __shared__ __align__(16) float As[16][68];
  __shared__ __align__(16) float Bs[16][68];
  int t = threadIdx.x;                 // 256
  int tx = t & 15, ty = t >> 4;
  int mt = blockIdx.x * 64;
  int ct = blockIdx.y;                 // head / column tile
  int n0 = ct * 64;

  int am = t >> 2;
  int ak = (t & 3) * 4;
  int bk = t >> 4;
  int bn = (t & 15) * 4;

  int mg = mt + am; if (mg >= M) mg = M - 1;
  const float* Arow = A + (size_t)mg * Kd;

  float acc[4][4] = {};
  for (int kc = 0; kc < Kd; kc += 16) {
    float4 av = *(const float4*)&Arow[kc + ak];
    As[ak + 0][am] = av.x;
    As[ak + 1][am] = av.y;
    As[ak + 2][am] = av.z;
    As[ak + 3][am] = av.w;
    *(float4*)&Bs[bk][bn] = *(const float4*)&Bm[(size_t)(kc + bk) * Ncols + n0 + bn];
    __syncthreads();
#pragma unroll
    for (int k = 0; k < 16; ++k) {
      float4 a4 = *(const float4*)&As[k][ty * 4];
      float4 b4 = *(const float4*)&Bs[k][tx * 4];
      float aa[4] = {a4.x, a4.y, a4.z, a4.w};
      float bb[4] = {b4.x, b4.y, b4.z, b4.w};
#pragma unroll
      for (int i = 0; i < 4; ++i)
#pragma unroll
        for (int j = 0; j < 4; ++j) acc[i][j] += aa[i] * bb[j];
    }
    __syncthreads();
  }

  float4 asv = *(const float4*)&att_src[n0 + tx * 4];
  float4 adv = *(const float4*)&att_dst[n0 + tx * 4];
#pragma unroll
  for (int i = 0; i < 4; ++i) {
    int m = mt + ty * 4 + i;
    bool valid = (m < M);
    if (valid) {
      if (OUTBF) {
        ushort4 u;
        u.x = f2bbits(acc[i][0]); u.y = f2bbits(acc[i][1]);
        u.z = f2bbits(acc[i][2]); u.w = f2bbits(acc[i][3]);
        *(ushort4*)&((unsigned short*)Cm)[(size_t)m * Ncols + n0 + tx * 4] = u;
      } else {
        *(float4*)&((float*)Cm)[(size_t)m * Ncols + n0 + tx * 4] =
            make_float4(acc[i][0], acc[i][1], acc[i][2], acc[i][3]);
      }
    }
    float ps = acc[i][0] * asv.x + acc[i][1] * asv.y +
               acc[i][2] * asv.z + acc[i][3] * asv.w;
    float pd = acc[i][0] * adv.x + acc[i][1] * adv.y +
               acc[i][2] * adv.z + acc[i][3] * adv.w;
#pragma unroll
    for (int off = 1; off < 16; off <<= 1) {
      ps += __shfl_xor(ps, off);
      pd += __shfl_xor(pd, off);
    }
    if (tx == 0 && valid) {
      a_s[(size_t)m * H + ct] = ps;
      a_d[(size_t)m * H + ct] = pd;
    }
  }
}

// ---------- fused GAT aggregation, H=8, bf16 features ----------
// One wave per dst. Pass C: lane owns 8 contiguous channels of head lane>>3
// (one 16B uint4 = 8 bf16 per edge per lane).
__global__ void gat_agg8_kernel(const int* __restrict__ rowptr,
                                const int* __restrict__ col,
                                const float* __restrict__ a_s,
                                const float* __restrict__ a_d,
                                const unsigned short* __restrict__ hfeat,
                                const float* __restrict__ bias,
                                float* __restrict__ out, int N) {
  int wave = threadIdx.x >> 6, lane = threadIdx.x & 63;
  int d = blockIdx.x * 4 + wave;
  if (d >= N) return;
  int beg = rowptr[d], end = rowptr[d + 1];

  float adv[8], mx[8], sm[8];
#pragma unroll
  for (int h = 0; h < 8; ++h) {
    adv[h] = a_d[(size_t)d * 8 + h];
    mx[h] = -1e30f;
    sm[h] = 0.f;
  }
  for (int i = beg + lane; i < end; i += 64) {
    int s = col[i];
#pragma unroll
    for (int h = 0; h < 8; ++h) {
      float v = a_s[(size_t)s * 8 + h] + adv[h];
      v = v > 0.f ? v : NEG * v;
      mx[h] = fmaxf(mx[h], v);
    }
  }
#pragma unroll
  for (int h = 0; h < 8; ++h)
    for (int off = 32; off; off >>= 1) mx[h] = fmaxf(mx[h], __shfl_xor(mx[h], off));
  for (int i = beg + lane; i < end; i += 64) {
    int s = col[i];
#pragma unroll
    for (int h = 0; h < 8; ++h) {
      float v = a_s[(size_t)s * 8 + h] + adv[h];
      v = v > 0.f ? v : NEG * v;
      sm[h] += __expf(v - mx[h]);
    }
  }
#pragma unroll
  for (int h = 0; h < 8; ++h) {
    for (int off = 32; off; off >>= 1) sm[h] += __shfl_xor(sm[h], off);
    sm[h] = 1.f / (sm[h] + 1e-16f);
  }

  // redistribute: this lane's head
  int hh = lane >> 3;
  float mxh = mx[0], smh = sm[0], adh = adv[0];
#pragma unroll
  for (int h = 1; h < 8; ++h) {
    bool p = (hh == h);
    mxh = p ? mx[h] : mxh;
    smh = p ? sm[h] : smh;
    adh = p ? adv[h] : adh;
  }

  const uint4* hf = (const uint4*)hfeat;   // 64 uint4 per node row (512 bf16)
  float acc[8] = {};
  for (int i = beg; i < end; ++i) {
    int s = col[i];                        // wave-uniform
    float e = a_s[(size_t)s * 8 + hh] + adh;
    e = e > 0.f ? e : NEG * e;
    float alpha = __expf(e - mxh) * smh;
    uint4 q = hf[(size_t)s * 64 + lane];
    acc[0] += alpha * blo(q.x); acc[1] += alpha * bhi(q.x);
    acc[2] += alpha * blo(q.y); acc[3] += alpha * bhi(q.y);
    acc[4] += alpha * blo(q.z); acc[5] += alpha * bhi(q.z);
    acc[6] += alpha * blo(q.w); acc[7] += alpha * bhi(q.w);
  }
  const float4* b4 = (const float4*)bias;   // bias[8*lane .. +7]
  float4 b0 = b4[2 * lane], b1 = b4[2 * lane + 1];
  float4 o0 = make_float4(elu1(acc[0] + b0.x), elu1(acc[1] + b0.y),
                          elu1(acc[2] + b0.z), elu1(acc[3] + b0.w));
  float4 o1 = make_float4(elu1(acc[4] + b1.x), elu1(acc[5] + b1.y),
                          elu1(acc[6] + b1.z), elu1(acc[7] + b1.w));
  float4* o4 = (float4*)out;
  o4[(size_t)d * 128 + 2 * lane]     = o0;
  o4[(size_t)d * 128 + 2 * lane + 1] = o1;
}

// H=1: one wave per dst, lane = channel (h2 stays f32; only 12.8 MB).
__global__ void gat_agg1_kernel(const int* __restrict__ rowptr,
                                const int* __restrict__ col,
                                const float* __restrict__ a_s,
                                const float* __restrict__ a_d,
                                const float* __restrict__ hfeat,
                                const float* __restrict__ bias,
                                float* __restrict__ out, int N) {
  int wave = threadIdx.x >> 6, lane = threadIdx.x & 63;
  int d = blockIdx.x * 4 + wave;
  if (d >= N) return;
  int beg = rowptr[d], end = rowptr[d + 1];
  float adv = a_d[d];
  float mx = -1e30f, sm = 0.f;
  for (int i = beg + lane; i < end; i += 64) {
    float v = a_s[col[i]] + adv;
    v = v > 0.f ? v : NEG * v;
    mx = fmaxf(mx, v);
  }
  for (int off = 32; off; off >>= 1) mx = fmaxf(mx, __shfl_xor(mx, off));
  for (int i = beg + lane; i < end; i += 64) {
    float v = a_s[col[i]] + adv;
    v = v > 0.f ? v : NEG * v;
    sm += __expf(v - mx);
  }
  for (int off = 32; off; off >>= 1) sm += __shfl_xor(sm, off);
  float sminv = 1.f / (sm + 1e-16f);
  float acc = 0.f;
  for (int i = beg; i < end; ++i) {
    int s = col[i];
    float v = a_s[s] + adv;
    v = v > 0.f ? v : NEG * v;
    float alpha = __expf(v - mx) * sminv;
    acc += alpha * hfeat[(size_t)s * 64 + lane];
  }
  out[(size_t)d * 64 + lane] = elu1(acc + bias[lane]);
}

// ---------- pooling (batch sorted) ----------
__global__ void pool_kernel(const float* __restrict__ out2,
                            const int* __restrict__ batch,
                            float* __restrict__ pooled, int N) {
  int wave = threadIdx.x >> 6, lane = threadIdx.x & 63;
  int seg = blockIdx.x * 4 + wave;
  int start = seg * 128;
  if (start >= N) return;
  int end = min(start + 128, N);
  int cur = batch[start];
  float acc = 0.f;
  for (int n = start; n < end; ++n) {
    int bn = batch[n];
    if (bn != cur) {
      unsafeAtomicAdd(&pooled[cur * 64 + lane], acc);
      acc = 0.f; cur = bn;
    }
    acc += out2[(size_t)n * 64 + lane];
  }
  unsafeAtomicAdd(&pooled[cur * 64 + lane], acc);
}

// ---------- MLP head + log_softmax ----------
__global__ void head_kernel(const float* __restrict__ pooled,
                            const float* __restrict__ lin1_w,
                            const float* __restrict__ lin1_b,
                            const float* __restrict__ lin2_w,
                            const float* __restrict__ lin2_b,
                            const int* __restrict__ flag,
                            void* __restrict__ outv) {
  __shared__ float P[B * C];
  __shared__ float Z[B * C];
  __shared__ float L[B * K];
  int t = threadIdx.x;  // 512
  for (int i = t; i < B * C; i += 512) P[i] = pooled[i];
  __syncthreads();
  for (int i = t; i < B * C; i += 512) {
    int r = i >> 6, c = i & 63;
    float acc = lin1_b[c];
    for (int k = 0; k < C; ++k) acc += P[r * C + k] * lin1_w[k * C + c];
    Z[i] = elu1(acc);
  }
  __syncthreads();
  for (int i = t; i < B * K; i += 512) {
    int r = i / K, c = i - r * K;
    float acc = lin2_b[c];
    for (int k = 0; k < C; ++k) acc += Z[r * C + k] * lin2_w[k * K + c];
    L[i] = acc;
  }
  __syncthreads();
  if (t < B) {
    float mx = -1e30f;
    for (int c = 0; c < K; ++c) mx = fmaxf(mx, L[t * K + c]);
    float s = 0.f;
    for (int c = 0; c < K; ++c) s += __expf(L[t * K + c] - mx);
    float lse = mx + __logf(s);
    int isbf = *flag;
    for (int c = 0; c < K; ++c) {
      float val = L[t * K + c] - lse;
      if (isbf) ((__hip_bfloat16*)outv)[t * K + c] = __float2bfloat16(val);
      else      ((float*)outv)[t * K + c] = val;
    }
  }
}

extern "C" void kernel_launch(void* const* d_in, const int* in_sizes, int n_in,
                              void* d_out, int out_size, void* d_ws, size_t ws_size,
                              hipStream_t stream) {
  const void* x_raw = d_in[0];
  const int*  ei    = (const int*)d_in[1];
  const int*  batch = (const int*)d_in[2];

  const int N    = in_sizes[2];
  const int E    = in_sizes[1] / 2;
  const int Etot = E + N;
  const int nb   = (N + 255) / 256;

  int*   flag = (int*)d_ws;
  float* ws   = (float*)d_ws;
  size_t off  = 16;

  float* xw  = ws + off; off += (size_t)N * F1;
  float* wts = ws + off; off += 104848;
  float* W1f  = wts + 0;
  float* as1w = wts + 65536;
  float* ad1w = wts + 66048;
  float* b1w  = wts + 66560;
  float* W2f  = wts + 67072;
  float* as2w = wts + 99840;
  float* ad2w = wts + 99904;
  float* b2w  = wts + 99968;
  float* l1w  = wts + 100032;
  float* l1b  = wts + 104128;
  float* l2w  = wts + 104192;
  float* l2b  = wts + 104832;

  unsigned short* h1bf = (unsigned short*)(ws + off); off += (size_t)N * 256; // N*512 bf16
  float* out1 = ws + off; off += (size_t)N * 512;
  float* as1  = ws + off; off += (size_t)N * H1;
  float* ad1  = ws + off; off += (size_t)N * H1;
  float* as2  = ws + off; off += (size_t)N;
  float* ad2  = ws + off; off += (size_t)N;
  float* pooled = ws + off; off += (size_t)B * C;

  int* ibase  = (int*)(ws + off);
  int* deg    = ibase;                 ibase += N;
  int* cursor = ibase;                 ibase += N;
  int* rowptr = ibase;                 ibase += N + 1;
  int* locals = ibase;                 ibase += N;
  int* bsum   = ibase;                 ibase += 256;
  int* col    = ibase;                 ibase += Etot;

  // layer-2 feature buffers alias xw (x dead after sgemm layer 1)
  float* h2   = xw;
  float* out2 = xw + (size_t)N * 64;

  // ---- dtype detect + canonicalize ----
  detect_kernel<<<1, 64, 0, stream>>>(x_raw, flag);
  {
    int n = in_sizes[0];
    int grid = (n + 255) / 256; if (grid > 8192) grid = 8192;
    convert_kernel<<<grid, 256, 0, stream>>>(d_in[0], xw, n, flag);
  }
  conv_wts_kernel<<<256, 256, 0, stream>>>(d_in[3], d_in[4], d_in[5], d_in[6],
                                           d_in[7], d_in[8], d_in[9], d_in[10],
                                           d_in[11], d_in[12], d_in[13], d_in[14],
                                           wts, flag);

  // ---- CSR build ----
  hipMemsetAsync(deg, 0, (size_t)N * 4, stream);
  hipMemsetAsync(pooled, 0, (size_t)B * C * 4, stream);
  deg_count_kernel<<<(Etot + 255) / 256, 256, 0, stream>>>(ei, E, Etot, deg);
  scan_block_kernel<<<nb, 256, 0, stream>>>(deg, locals, bsum, N);
  scan_sums_kernel<<<1, 256, 0, stream>>>(bsum, nb);
  scan_add_kernel<<<nb, 256, 0, stream>>>(locals, bsum, rowptr, cursor, N, Etot);
  csr_fill_kernel<<<(Etot + 255) / 256, 256, 0, stream>>>(ei, E, Etot, cursor, col);

  // ---- layer 1: h1 = xw @ W1 (bf16 out, attn coefs f32, fused) ----
  {
    dim3 grid((N + 63) / 64, 8);
    sgemm_attn_kernel<H1, true><<<grid, 256, 0, stream>>>(xw, W1f, as1w, ad1w,
                                                          h1bf, as1, ad1, N, F1, 512);
  }
  gat_agg8_kernel<<<(N + 3) / 4, 256, 0, stream>>>(rowptr, col, as1, ad1, h1bf, b1w, out1, N);

  // ---- layer 2: h2 = out1 @ W2 (f32 out, fused attn) ----
  {
    dim3 grid((N + 63) / 64, 1);
    sgemm_attn_kernel<1, false><<<grid, 256, 0, stream>>>(out1, W2f, as2w, ad2w,
                                                          h2, as2, ad2, N, 512, 64);
  }
  gat_agg1_kernel<<<(N + 3) / 4, 256, 0, stream>>>(rowptr, col, as2, ad2, h2, b2w, out2, N);

  // ---- pool + head ----
  pool_kernel<<<(N + 511) / 512, 256, 0, stream>>>(out2, batch, pooled, N);
  head_kernel<<<1, 512, 0, stream>>>(pooled, l1w, l1b, l2w, l2b, flag, (void*)d_out);
}

// Round 7
// 447.429 us; speedup vs baseline: 4.1236x; 1.2004x over previous
//
#include <hip/hip_runtime.h>
#include <hip/hip_bf16.h>

#define DEV static __device__ __forceinline__

constexpr int F1 = 128;   // input features
constexpr int H1 = 8;     // heads layer1
constexpr int C  = 64;    // channels per head
constexpr int B  = 64;    // graphs
constexpr int K  = 10;    // classes
constexpr float NEG = 0.2f;

typedef __attribute__((ext_vector_type(8))) short short8;
typedef __attribute__((ext_vector_type(4))) float floatx4;

DEV float b2f(__hip_bfloat16 x) { return __bfloat162float(x); }
DEV float elu1(float v) { return v > 0.f ? v : (__expf(v) - 1.f); }
DEV unsigned short f2bbits(float f) {
  __hip_bfloat16 b = __float2bfloat16(f);
  return *(unsigned short*)&b;
}
DEV float blo(unsigned u) { return __uint_as_float(u << 16); }
DEV float bhi(unsigned u) { return __uint_as_float(u & 0xffff0000u); }

// ---------- dtype detection + canonicalization ----------
__global__ void detect_kernel(const void* xraw, int* flag) {
  const __hip_bfloat16* xb = (const __hip_bfloat16*)xraw;
  int lane = threadIdx.x & 63;
  int bad = 0;
  for (int it = 0; it < 8; ++it) {
    int i = it * 64 + lane;
    float v = b2f(xb[2 * i]);
    if (!(fabsf(v) < 1e4f)) bad++;
  }
  for (int off = 32; off; off >>= 1) bad += __shfl_down(bad, off);
  if (lane == 0) *flag = (bad < 64) ? 1 : 0;   // 1 = bf16, 0 = f32
}

// x -> bf16 bits
__global__ void conv_x_kernel(const void* __restrict__ raw,
                              unsigned short* __restrict__ dst, int n,
                              const int* __restrict__ flag) {
  int isbf = *flag;
  for (int i = blockIdx.x * blockDim.x + threadIdx.x; i < n;
       i += gridDim.x * blockDim.x) {
    if (isbf) dst[i] = ((const unsigned short*)raw)[i];
    else      dst[i] = f2bbits(((const float*)raw)[i]);
  }
}

// All 12 small weight tensors -> f32, ONE dispatch.
#define CVT(p, i) (isbf ? b2f(((const __hip_bfloat16*)(p))[i]) : ((const float*)(p))[i])
__global__ void conv_wts_kernel(const void* s0, const void* s1, const void* s2,
                                const void* s3, const void* s4, const void* s5,
                                const void* s6, const void* s7, const void* s8,
                                const void* s9, const void* s10, const void* s11,
                                float* __restrict__ dst,
                                const int* __restrict__ flag) {
  int isbf = *flag;
  int gid = blockIdx.x * 256 + threadIdx.x;
  int stride = gridDim.x * 256;
  for (int i = gid; i < 65536; i += stride) dst[0      + i] = CVT(s0, i);  // W1
  for (int i = gid; i < 512;   i += stride) dst[65536  + i] = CVT(s1, i);  // att_src1
  for (int i = gid; i < 512;   i += stride) dst[66048  + i] = CVT(s2, i);  // att_dst1
  for (int i = gid; i < 512;   i += stride) dst[66560  + i] = CVT(s3, i);  // b1
  for (int i = gid; i < 32768; i += stride) dst[67072  + i] = CVT(s4, i);  // W2
  for (int i = gid; i < 64;    i += stride) dst[99840  + i] = CVT(s5, i);  // att_src2
  for (int i = gid; i < 64;    i += stride) dst[99904  + i] = CVT(s6, i);  // att_dst2
  for (int i = gid; i < 64;    i += stride) dst[99968  + i] = CVT(s7, i);  // b2
  for (int i = gid; i < 4096;  i += stride) dst[100032 + i] = CVT(s8, i);  // lin1_w
  for (int i = gid; i < 64;    i += stride) dst[104128 + i] = CVT(s9, i);  // lin1_b
  for (int i = gid; i < 640;   i += stride) dst[104192 + i] = CVT(s10, i); // lin2_w
  for (int i = gid; i < 10;    i += stride) dst[104832 + i] = CVT(s11, i); // lin2_b
}

// W1 -> MFMA B-fragment order: frag[nt][ks][lane][j] = W1[ks*32+(lane>>4)*8+j][nt*16+(lane&15)]
__global__ void w1frag_kernel(const void* __restrict__ w1raw,
                              unsigned short* __restrict__ out,
                              const int* __restrict__ flag) {
  int isbf = *flag;
  int t = blockIdx.x * 256 + threadIdx.x;   // 8192 = 32nt * 4ks * 64lane
  if (t >= 8192) return;
  int lane = t & 63, ks = (t >> 6) & 3, nt = t >> 8;
  for (int j = 0; j < 8; ++j) {
    int k = ks * 32 + (lane >> 4) * 8 + j;
    int n = nt * 16 + (lane & 15);
    out[t * 8 + j] = f2bbits(CVT(w1raw, k * 512 + n));
  }
}

// ---------- CSR construction (by destination) ----------
__global__ void deg_count_kernel(const int* __restrict__ ei, int E, int Etot,
                                 int* __restrict__ deg) {
  int e = blockIdx.x * blockDim.x + threadIdx.x;
  if (e >= Etot) return;
  int d = (e < E) ? ei[E + e] : e - E;
  atomicAdd(&deg[d], 1);
}

__global__ void scan_block_kernel(const int* __restrict__ deg,
                                  int* __restrict__ local,
                                  int* __restrict__ bsum, int N) {
  __shared__ int tmp[256];
  int t = threadIdx.x;
  int i = blockIdx.x * 256 + t;
  int v = (i < N) ? deg[i] : 0;
  tmp[t] = v;
  __syncthreads();
  for (int off = 1; off < 256; off <<= 1) {
    int u = (t >= off) ? tmp[t - off] : 0;
    __syncthreads();
    tmp[t] += u;
    __syncthreads();
  }
  if (i < N) local[i] = tmp[t] - v;
  if (t == 255) bsum[blockIdx.x] = tmp[255];
}

__global__ void scan_sums_kernel(int* __restrict__ bsum, int nb) {
  __shared__ int tmp[256];
  int t = threadIdx.x;
  int v0 = (t < nb) ? bsum[t] : 0;
  tmp[t] = v0;
  __syncthreads();
  for (int off = 1; off < 256; off <<= 1) {
    int u = (t >= off) ? tmp[t - off] : 0;
    __syncthreads();
    tmp[t] += u;
    __syncthreads();
  }
  if (t < nb) bsum[t] = tmp[t] - v0;
}

__global__ void scan_add_kernel(const int* __restrict__ local,
                                const int* __restrict__ bsum,
                                int* __restrict__ rowptr,
                                int* __restrict__ cursor, int N, int Etot) {
  int i = blockIdx.x * 256 + threadIdx.x;
  if (i < N) {
    int r = local[i] + bsum[i >> 8];
    rowptr[i] = r;
    cursor[i] = r;
  }
  if (i == 0) rowptr[N] = Etot;
}

__global__ void csr_fill_kernel(const int* __restrict__ ei, int E, int Etot,
                                int* __restrict__ cursor, int* __restrict__ col) {
  int e = blockIdx.x * blockDim.x + threadIdx.x;
  if (e >= Etot) return;
  int s, d;
  if (e < E) { s = ei[e]; d = ei[E + e]; } else { s = d = e - E; }
  int pos = atomicAdd(&cursor[d], 1);
  col[pos] = s;
}

// ---------- layer 1: MFMA bf16 GEMM + fused attention coefs ----------
// h1[N,512] = x[N,128] @ W1[128,512].  Block: 128 rows x 128 cols (2 heads),
// 4 waves x (32 rows x 128 cols).  A-frags from global, B-frags from LDS
// (pre-transformed W1frag).  Epilogue: bf16 store + a_s/a_d via 16-lane reduce.
__global__ __launch_bounds__(256) void gemm1_mfma_kernel(
    const unsigned short* __restrict__ xbf,     // N x 128 bf16
    const unsigned short* __restrict__ W1frag,  // [32][4][64][8] bf16
    const float* __restrict__ att_src,          // 512
    const float* __restrict__ att_dst,
    unsigned short* __restrict__ h1,            // N x 512 bf16
    float* __restrict__ a_s, float* __restrict__ a_d,   // N x 8
    int N) {
  __shared__ unsigned short Bls[16384];         // 32 KB: [8nt][4ks][64][8]
  int t = threadIdx.x;
  int w = t >> 6, lane = t & 63;
  int hp = blockIdx.y;                          // head pair: cols [hp*128, +128)
  {
    const uint4* src = (const uint4*)(W1frag + (size_t)hp * 16384);
    uint4* dstp = (uint4*)Bls;
    for (int i = t; i < 2048; i += 256) dstp[i] = src[i];
  }
  __syncthreads();

  int quad = lane >> 4, l16 = lane & 15;
  int rowbase = blockIdx.x * 128 + w * 32;

  short8 afr[2][4];
#pragma unroll
  for (int mt = 0; mt < 2; ++mt) {
    int r = rowbase + mt * 16 + l16; if (r >= N) r = N - 1;
    const unsigned short* rp = xbf + (size_t)r * 128 + quad * 8;
#pragma unroll
    for (int ks = 0; ks < 4; ++ks)
      afr[mt][ks] = *(const short8*)(rp + ks * 32);
  }

  floatx4 acc[2][8] = {};
#pragma unroll
  for (int nt = 0; nt < 8; ++nt) {
#pragma unroll
    for (int ks = 0; ks < 4; ++ks) {
      short8 b = *(const short8*)&Bls[((nt * 4 + ks) * 64 + lane) * 8];
      acc[0][nt] = __builtin_amdgcn_mfma_f32_16x16x32_bf16(afr[0][ks], b, acc[0][nt], 0, 0, 0);
      acc[1][nt] = __builtin_amdgcn_mfma_f32_16x16x32_bf16(afr[1][ks], b, acc[1][nt], 0, 0, 0);
    }
  }

  float asw[8], adw[8];
#pragma unroll
  for (int nt = 0; nt < 8; ++nt) {
    asw[nt] = att_src[hp * 128 + nt * 16 + l16];
    adw[nt] = att_dst[hp * 128 + nt * 16 + l16];
  }
#pragma unroll
  for (int mt = 0; mt < 2; ++mt) {
    float ps[2][4] = {}, pd[2][4] = {};
#pragma unroll
    for (int nt = 0; nt < 8; ++nt) {
      int hl = nt >> 2;
#pragma unroll
      for (int r = 0; r < 4; ++r) {
        float v = acc[mt][nt][r];
        int row = rowbase + mt * 16 + quad * 4 + r;
        if (row < N)
          h1[(size_t)row * 512 + hp * 128 + nt * 16 + l16] = f2bbits(v);
        ps[hl][r] += v * asw[nt];
        pd[hl][r] += v * adw[nt];
      }
    }
#pragma unroll
    for (int hl = 0; hl < 2; ++hl)
#pragma unroll
      for (int r = 0; r < 4; ++r) {
        float p = ps[hl][r], q = pd[hl][r];
#pragma unroll
        for (int off = 1; off < 16; off <<= 1) {
          p += __shfl_xor(p, off);
          q += __shfl_xor(q, off);
        }
        int row = rowbase + mt * 16 + quad * 4 + r;
        if (l16 == 0 && row < N) {
          a_s[(size_t)row * 8 + hp * 2 + hl] = p;
          a_d[(size_t)row * 8 + hp * 2 + hl] = q;
        }
      }
  }
}

// ---------- layer 2: tiled f32 SGEMM + fused attention epilogue ----------
template <int H>
__global__ void sgemm_attn_kernel(const float* __restrict__ A,
                                  const float* __restrict__ Bm,
                                  const float* __restrict__ att_src,
                                  const float* __restrict__ att_dst,
                                  float* __restrict__ Cm,
                                  float* __restrict__ a_s,
                                  float* __restrict__ a_d,
                                  int M, int Kd, int Ncols) {
  __shared__ __align__(16) float As[16][68];
  __shared__ __align__(16) float Bs[16][68];
  int t = threadIdx.x;
  int tx = t & 15, ty = t >> 4;
  int mt = blockIdx.x * 64;
  int ct = blockIdx.y;
  int n0 = ct * 64;

  int am = t >> 2;
  int ak = (t & 3) * 4;
  int bk = t >> 4;
  int bn = (t & 15) * 4;

  int mg = mt + am; if (mg >= M) mg = M - 1;
  const float* Arow = A + (size_t)mg * Kd;

  float acc[4][4] = {};
  for (int kc = 0; kc < Kd; kc += 16) {
    float4 av = *(const float4*)&Arow[kc + ak];
    As[ak + 0][am] = av.x;
    As[ak + 1][am] = av.y;
    As[ak + 2][am] = av.z;
    As[ak + 3][am] = av.w;
    *(float4*)&Bs[bk][bn] = *(const float4*)&Bm[(size_t)(kc + bk) * Ncols + n0 + bn];
    __syncthreads();
#pragma unroll
    for (int k = 0; k < 16; ++k) {
      float4 a4 = *(const float4*)&As[k][ty * 4];
      float4 b4 = *(const float4*)&Bs[k][tx * 4];
      float aa[4] = {a4.x, a4.y, a4.z, a4.w};
      float bb[4] = {b4.x, b4.y, b4.z, b4.w};
#pragma unroll
      for (int i = 0; i < 4; ++i)
#pragma unroll
        for (int j = 0; j < 4; ++j) acc[i][j] += aa[i] * bb[j];
    }
    __syncthreads();
  }

  float4 asv = *(const float4*)&att_src[n0 + tx * 4];
  float4 adv = *(const float4*)&att_dst[n0 + tx * 4];
#pragma unroll
  for (int i = 0; i < 4; ++i) {
    int m = mt + ty * 4 + i;
    bool valid = (m < M);
    if (valid)
      *(float4*)&Cm[(size_t)m * Ncols + n0 + tx * 4] =
          make_float4(acc[i][0], acc[i][1], acc[i][2], acc[i][3]);
    float ps = acc[i][0] * asv.x + acc[i][1] * asv.y +
               acc[i][2] * asv.z + acc[i][3] * asv.w;
    float pd = acc[i][0] * adv.x + acc[i][1] * adv.y +
               acc[i][2] * adv.z + acc[i][3] * adv.w;
#pragma unroll
    for (int off = 1; off < 16; off <<= 1) {
      ps += __shfl_xor(ps, off);
      pd += __shfl_xor(pd, off);
    }
    if (tx == 0 && valid) {
      a_s[(size_t)m * H + ct] = ps;
      a_d[(size_t)m * H + ct] = pd;
    }
  }
}

// ---------- single-pass GAT aggregation, H=8, bf16 features ----------
// softmax without max-subtraction (shift-invariant; |logits| ~ O(10), exp-safe).
// One wave per dst; lane owns 8 channels of head lane>>3; one edge sweep.
__global__ void gat_agg8_kernel(const int* __restrict__ rowptr,
                                const int* __restrict__ col,
                                const float* __restrict__ a_s,
                                const float* __restrict__ a_d,
                                const unsigned short* __restrict__ hfeat,
                                const float* __restrict__ bias,
                                float* __restrict__ out, int N) {
  int wave = threadIdx.x >> 6, lane = threadIdx.x & 63;
  int d = blockIdx.x * 4 + wave;
  if (d >= N) return;
  int beg = rowptr[d], end = rowptr[d + 1];
  int hh = lane >> 3;
  float adh = a_d[(size_t)d * 8 + hh];

  const uint4* hf = (const uint4*)hfeat;
  float acc[8] = {};
  float wsum = 0.f;
  for (int i = beg; i < end; ++i) {
    int s = col[i];                          // wave-uniform
    float e = a_s[(size_t)s * 8 + hh] + adh;
    e = e > 0.f ? e : NEG * e;
    float wv = __expf(e);
    wsum += wv;
    uint4 q = hf[(size_t)s * 64 + lane];
    acc[0] += wv * blo(q.x); acc[1] += wv * bhi(q.x);
    acc[2] += wv * blo(q.y); acc[3] += wv * bhi(q.y);
    acc[4] += wv * blo(q.z); acc[5] += wv * bhi(q.z);
    acc[6] += wv * blo(q.w); acc[7] += wv * bhi(q.w);
  }
  float winv = 1.f / (wsum + 1e-16f);
  const float4* b4 = (const float4*)bias;
  float4 b0 = b4[2 * lane], b1 = b4[2 * lane + 1];
  float4 o0 = make_float4(elu1(acc[0] * winv + b0.x), elu1(acc[1] * winv + b0.y),
                          elu1(acc[2] * winv + b0.z), elu1(acc[3] * winv + b0.w));
  float4 o1 = make_float4(elu1(acc[4] * winv + b1.x), elu1(acc[5] * winv + b1.y),
                          elu1(acc[6] * winv + b1.z), elu1(acc[7] * winv + b1.w));
  float4* o4 = (float4*)out;
  o4[(size_t)d * 128 + 2 * lane]     = o0;
  o4[(size_t)d * 128 + 2 * lane + 1] = o1;
}

// single-pass, H=1: lane = channel.
__global__ void gat_agg1_kernel(const int* __restrict__ rowptr,
                                const int* __restrict__ col,
                                const float* __restrict__ a_s,
                                const float* __restrict__ a_d,
                                const float* __restrict__ hfeat,
                                const float* __restrict__ bias,
                                float* __restrict__ out, int N) {
  int wave = threadIdx.x >> 6, lane = threadIdx.x & 63;
  int d = blockIdx.x * 4 + wave;
  if (d >= N) return;
  int beg = rowptr[d], end = rowptr[d + 1];
  float adv = a_d[d];
  float acc = 0.f, wsum = 0.f;
  for (int i = beg; i < end; ++i) {
    int s = col[i];
    float v = a_s[s] + adv;
    v = v > 0.f ? v : NEG * v;
    float wv = __expf(v);
    wsum += wv;
    acc += wv * hfeat[(size_t)s * 64 + lane];
  }
  out[(size_t)d * 64 + lane] = elu1(acc / (wsum + 1e-16f) + bias[lane]);
}

// ---------- pooling (batch sorted) ----------
__global__ void pool_kernel(const float* __restrict__ out2,
                            const int* __restrict__ batch,
                            float* __restrict__ pooled, int N) {
  int wave = threadIdx.x >> 6, lane = threadIdx.x & 63;
  int seg = blockIdx.x * 4 + wave;
  int start = seg * 128;
  if (start >= N) return;
  int end = min(start + 128, N);
  int cur = batch[start];
  float acc = 0.f;
  for (int n = start; n < end; ++n) {
    int bn = batch[n];
    if (bn != cur) {
      unsafeAtomicAdd(&pooled[cur * 64 + lane], acc);
      acc = 0.f; cur = bn;
    }
    acc += out2[(size_t)n * 64 + lane];
  }
  unsafeAtomicAdd(&pooled[cur * 64 + lane], acc);
}

// ---------- MLP head + log_softmax ----------
__global__ void head_kernel(const float* __restrict__ pooled,
                            const float* __restrict__ lin1_w,
                            const float* __restrict__ lin1_b,
                            const float* __restrict__ lin2_w,
                            const float* __restrict__ lin2_b,
                            const int* __restrict__ flag,
                            void* __restrict__ outv) {
  __shared__ float P[B * C];
  __shared__ float Z[B * C];
  __shared__ float L[B * K];
  int t = threadIdx.x;  // 512
  for (int i = t; i < B * C; i += 512) P[i] = pooled[i];
  __syncthreads();
  for (int i = t; i < B * C; i += 512) {
    int r = i >> 6, c = i & 63;
    float acc = lin1_b[c];
    for (int k = 0; k < C; ++k) acc += P[r * C + k] * lin1_w[k * C + c];
    Z[i] = elu1(acc);
  }
  __syncthreads();
  for (int i = t; i < B * K; i += 512) {
    int r = i / K, c = i - r * K;
    float acc = lin2_b[c];
    for (int k = 0; k < C; ++k) acc += Z[r * C + k] * lin2_w[k * K + c];
    L[i] = acc;
  }
  __syncthreads();
  if (t < B) {
    float mx = -1e30f;
    for (int c = 0; c < K; ++c) mx = fmaxf(mx, L[t * K + c]);
    float s = 0.f;
    for (int c = 0; c < K; ++c) s += __expf(L[t * K + c] - mx);
    float lse = mx + __logf(s);
    int isbf = *flag;
    for (int c = 0; c < K; ++c) {
      float val = L[t * K + c] - lse;
      if (isbf) ((__hip_bfloat16*)outv)[t * K + c] = __float2bfloat16(val);
      else      ((float*)outv)[t * K + c] = val;
    }
  }
}

extern "C" void kernel_launch(void* const* d_in, const int* in_sizes, int n_in,
                              void* d_out, int out_size, void* d_ws, size_t ws_size,
                              hipStream_t stream) {
  const void* x_raw = d_in[0];
  const int*  ei    = (const int*)d_in[1];
  const int*  batch = (const int*)d_in[2];

  const int N    = in_sizes[2];
  const int E    = in_sizes[1] / 2;
  const int Etot = E + N;
  const int nb   = (N + 255) / 256;

  int*   flag = (int*)d_ws;
  float* ws   = (float*)d_ws;
  size_t off  = 16;

  float* wts = ws + off; off += 104848;
  float* as1w = wts + 65536;
  float* ad1w = wts + 66048;
  float* b1w  = wts + 66560;
  float* W2f  = wts + 67072;
  float* as2w = wts + 99840;
  float* ad2w = wts + 99904;
  float* b2w  = wts + 99968;
  float* l1w  = wts + 100032;
  float* l1b  = wts + 104128;
  float* l2w  = wts + 104192;
  float* l2b  = wts + 104832;

  unsigned short* xbf    = (unsigned short*)(ws + off); off += (size_t)N * 64;   // N*128 bf16
  unsigned short* w1frag = (unsigned short*)(ws + off); off += 32768;            // 65536 bf16
  unsigned short* h1bf   = (unsigned short*)(ws + off); off += (size_t)N * 256;  // N*512 bf16
  float* out1 = ws + off; off += (size_t)N * 512;
  float* h2   = ws + off; off += (size_t)N * 64;
  float* out2 = ws + off; off += (size_t)N * 64;
  float* as1  = ws + off; off += (size_t)N * H1;
  float* ad1  = ws + off; off += (size_t)N * H1;
  float* as2  = ws + off; off += (size_t)N;
  float* ad2  = ws + off; off += (size_t)N;
  float* pooled = ws + off; off += (size_t)B * C;

  int* ibase  = (int*)(ws + off);
  int* deg    = ibase;                 ibase += N;
  int* cursor = ibase;                 ibase += N;
  int* rowptr = ibase;                 ibase += N + 1;
  int* locals = ibase;                 ibase += N;
  int* bsum   = ibase;                 ibase += 256;
  int* col    = ibase;                 ibase += Etot;

  // ---- dtype detect + canonicalize ----
  detect_kernel<<<1, 64, 0, stream>>>(x_raw, flag);
  {
    int n = in_sizes[0];
    int grid = (n + 255) / 256; if (grid > 4096) grid = 4096;
    conv_x_kernel<<<grid, 256, 0, stream>>>(x_raw, xbf, n, flag);
  }
  conv_wts_kernel<<<256, 256, 0, stream>>>(d_in[3], d_in[4], d_in[5], d_in[6],
                                           d_in[7], d_in[8], d_in[9], d_in[10],
                                           d_in[11], d_in[12], d_in[13], d_in[14],
                                           wts, flag);
  w1frag_kernel<<<32, 256, 0, stream>>>(d_in[3], w1frag, flag);

  // ---- CSR build ----
  hipMemsetAsync(deg, 0, (size_t)N * 4, stream);
  hipMemsetAsync(pooled, 0, (size_t)B * C * 4, stream);
  deg_count_kernel<<<(Etot + 255) / 256, 256, 0, stream>>>(ei, E, Etot, deg);
  scan_block_kernel<<<nb, 256, 0, stream>>>(deg, locals, bsum, N);
  scan_sums_kernel<<<1, 256, 0, stream>>>(bsum, nb);
  scan_add_kernel<<<nb, 256, 0, stream>>>(locals, bsum, rowptr, cursor, N, Etot);
  csr_fill_kernel<<<(Etot + 255) / 256, 256, 0, stream>>>(ei, E, Etot, cursor, col);

  // ---- layer 1: MFMA GEMM + fused attn coefs ----
  {
    dim3 grid((N + 127) / 128, 4);
    gemm1_mfma_kernel<<<grid, 256, 0, stream>>>(xbf, w1frag, as1w, ad1w,
                                                h1bf, as1, ad1, N);
  }
  gat_agg8_kernel<<<(N + 3) / 4, 256, 0, stream>>>(rowptr, col, as1, ad1, h1bf, b1w, out1, N);

  // ---- layer 2: f32 SGEMM + fused attn coefs ----
  {
    dim3 grid((N + 63) / 64, 1);
    sgemm_attn_kernel<1><<<grid, 256, 0, stream>>>(out1, W2f, as2w, ad2w,
                                                   h2, as2, ad2, N, 512, 64);
  }
  gat_agg1_kernel<<<(N + 3) / 4, 256, 0, stream>>>(rowptr, col, as2, ad2, h2, b2w, out2, N);

  // ---- pool + head ----
  pool_kernel<<<(N + 511) / 512, 256, 0, stream>>>(out2, batch, pooled, N);
  head_kernel<<<1, 512, 0, stream>>>(pooled, l1w, l1b, l2w, l2b, flag, (void*)d_out);
}

// Round 8
// 375.127 us; speedup vs baseline: 4.9184x; 1.1927x over previous
//
#include <hip/hip_runtime.h>
#include <hip/hip_bf16.h>

#define DEV static __device__ __forceinline__

constexpr int F1 = 128;   // input features
constexpr int H1 = 8;     // heads layer1
constexpr int C  = 64;    // channels per head
constexpr int B  = 64;    // graphs
constexpr int K  = 10;    // classes
constexpr float NEG = 0.2f;

typedef __attribute__((ext_vector_type(8))) short short8;
typedef __attribute__((ext_vector_type(4))) float floatx4;

DEV float b2f(__hip_bfloat16 x) { return __bfloat162float(x); }
DEV float elu1(float v) { return v > 0.f ? v : (__expf(v) - 1.f); }
DEV unsigned short f2bbits(float f) {
  __hip_bfloat16 b = __float2bfloat16(f);
  return *(unsigned short*)&b;
}
DEV float blo(unsigned u) { return __uint_as_float(u << 16); }
DEV float bhi(unsigned u) { return __uint_as_float(u & 0xffff0000u); }
DEV unsigned pack2(float lo, float hi) {
  return (unsigned)f2bbits(lo) | ((unsigned)f2bbits(hi) << 16);
}

// ---------- dtype detection + canonicalization ----------
__global__ void detect_kernel(const void* xraw, int* flag) {
  const __hip_bfloat16* xb = (const __hip_bfloat16*)xraw;
  int lane = threadIdx.x & 63;
  int bad = 0;
  for (int it = 0; it < 8; ++it) {
    int i = it * 64 + lane;
    float v = b2f(xb[2 * i]);
    if (!(fabsf(v) < 1e4f)) bad++;
  }
  for (int off = 32; off; off >>= 1) bad += __shfl_down(bad, off);
  if (lane == 0) *flag = (bad < 64) ? 1 : 0;   // 1 = bf16, 0 = f32
}

// x -> bf16 bits
__global__ void conv_x_kernel(const void* __restrict__ raw,
                              unsigned short* __restrict__ dst, int n,
                              const int* __restrict__ flag) {
  int isbf = *flag;
  for (int i = blockIdx.x * blockDim.x + threadIdx.x; i < n;
       i += gridDim.x * blockDim.x) {
    if (isbf) dst[i] = ((const unsigned short*)raw)[i];
    else      dst[i] = f2bbits(((const float*)raw)[i]);
  }
}

// All 12 small weight tensors -> f32, ONE dispatch.
#define CVT(p, i) (isbf ? b2f(((const __hip_bfloat16*)(p))[i]) : ((const float*)(p))[i])
__global__ void conv_wts_kernel(const void* s0, const void* s1, const void* s2,
                                const void* s3, const void* s4, const void* s5,
                                const void* s6, const void* s7, const void* s8,
                                const void* s9, const void* s10, const void* s11,
                                float* __restrict__ dst,
                                const int* __restrict__ flag) {
  int isbf = *flag;
  int gid = blockIdx.x * 256 + threadIdx.x;
  int stride = gridDim.x * 256;
  for (int i = gid; i < 65536; i += stride) dst[0      + i] = CVT(s0, i);  // W1
  for (int i = gid; i < 512;   i += stride) dst[65536  + i] = CVT(s1, i);  // att_src1
  for (int i = gid; i < 512;   i += stride) dst[66048  + i] = CVT(s2, i);  // att_dst1
  for (int i = gid; i < 512;   i += stride) dst[66560  + i] = CVT(s3, i);  // b1
  for (int i = gid; i < 32768; i += stride) dst[67072  + i] = CVT(s4, i);  // W2
  for (int i = gid; i < 64;    i += stride) dst[99840  + i] = CVT(s5, i);  // att_src2
  for (int i = gid; i < 64;    i += stride) dst[99904  + i] = CVT(s6, i);  // att_dst2
  for (int i = gid; i < 64;    i += stride) dst[99968  + i] = CVT(s7, i);  // b2
  for (int i = gid; i < 4096;  i += stride) dst[100032 + i] = CVT(s8, i);  // lin1_w
  for (int i = gid; i < 64;    i += stride) dst[104128 + i] = CVT(s9, i);  // lin1_b
  for (int i = gid; i < 640;   i += stride) dst[104192 + i] = CVT(s10, i); // lin2_w
  for (int i = gid; i < 10;    i += stride) dst[104832 + i] = CVT(s11, i); // lin2_b
}

// W1 and W2 -> MFMA B-fragment order, one dispatch.
// w1frag[nt<32][ks<4][lane][j<8] = W1[ks*32+(lane>>4)*8+j][nt*16+(lane&15)]
// w2frag[ks<16][nt<4][lane][j<8] = W2[ks*32+(lane>>4)*8+j][nt*16+(lane&15)]
__global__ void prep_frags_kernel(const void* __restrict__ w1raw,
                                  const void* __restrict__ w2raw,
                                  unsigned short* __restrict__ o1,
                                  unsigned short* __restrict__ o2,
                                  const int* __restrict__ flag) {
  int isbf = *flag;
  int t = blockIdx.x * 256 + threadIdx.x;   // 12288 total
  if (t < 8192) {
    int lane = t & 63, ks = (t >> 6) & 3, nt = t >> 8;
    for (int j = 0; j < 8; ++j) {
      int k = ks * 32 + (lane >> 4) * 8 + j;
      int n = nt * 16 + (lane & 15);
      o1[t * 8 + j] = f2bbits(CVT(w1raw, k * 512 + n));
    }
  } else if (t < 12288) {
    int u = t - 8192;
    int lane = u & 63, nt = (u >> 6) & 3, ks = u >> 8;
    for (int j = 0; j < 8; ++j) {
      int k = ks * 32 + (lane >> 4) * 8 + j;
      int n = nt * 16 + (lane & 15);
      o2[u * 8 + j] = f2bbits(CVT(w2raw, k * 64 + n));
    }
  }
}

// ---------- CSR construction (by destination) ----------
__global__ void deg_count_kernel(const int* __restrict__ ei, int E, int Etot,
                                 int* __restrict__ deg) {
  int e = blockIdx.x * blockDim.x + threadIdx.x;
  if (e >= Etot) return;
  int d = (e < E) ? ei[E + e] : e - E;
  atomicAdd(&deg[d], 1);
}

__global__ void scan_block_kernel(const int* __restrict__ deg,
                                  int* __restrict__ local,
                                  int* __restrict__ bsum, int N) {
  __shared__ int tmp[256];
  int t = threadIdx.x;
  int i = blockIdx.x * 256 + t;
  int v = (i < N) ? deg[i] : 0;
  tmp[t] = v;
  __syncthreads();
  for (int off = 1; off < 256; off <<= 1) {
    int u = (t >= off) ? tmp[t - off] : 0;
    __syncthreads();
    tmp[t] += u;
    __syncthreads();
  }
  if (i < N) local[i] = tmp[t] - v;
  if (t == 255) bsum[blockIdx.x] = tmp[255];
}

__global__ void scan_sums_kernel(int* __restrict__ bsum, int nb) {
  __shared__ int tmp[256];
  int t = threadIdx.x;
  int v0 = (t < nb) ? bsum[t] : 0;
  tmp[t] = v0;
  __syncthreads();
  for (int off = 1; off < 256; off <<= 1) {
    int u = (t >= off) ? tmp[t - off] : 0;
    __syncthreads();
    tmp[t] += u;
    __syncthreads();
  }
  if (t < nb) bsum[t] = tmp[t] - v0;
}

__global__ void scan_add_kernel(const int* __restrict__ local,
                                const int* __restrict__ bsum,
                                int* __restrict__ rowptr,
                                int* __restrict__ cursor, int N, int Etot) {
  int i = blockIdx.x * 256 + threadIdx.x;
  if (i < N) {
    int r = local[i] + bsum[i >> 8];
    rowptr[i] = r;
    cursor[i] = r;
  }
  if (i == 0) rowptr[N] = Etot;
}

__global__ void csr_fill_kernel(const int* __restrict__ ei, int E, int Etot,
                                int* __restrict__ cursor, int* __restrict__ col) {
  int e = blockIdx.x * blockDim.x + threadIdx.x;
  if (e >= Etot) return;
  int s, d;
  if (e < E) { s = ei[e]; d = ei[E + e]; } else { s = d = e - E; }
  int pos = atomicAdd(&cursor[d], 1);
  col[pos] = s;
}

// ---------- layer 1: MFMA bf16 GEMM + fused attention coefs ----------
__global__ __launch_bounds__(256) void gemm1_mfma_kernel(
    const unsigned short* __restrict__ xbf,     // N x 128 bf16
    const unsigned short* __restrict__ W1frag,  // [32][4][64][8] bf16
    const float* __restrict__ att_src,          // 512
    const float* __restrict__ att_dst,
    unsigned short* __restrict__ h1,            // N x 512 bf16
    float* __restrict__ a_s, float* __restrict__ a_d,   // N x 8
    int N) {
  __shared__ unsigned short Bls[16384];         // 32 KB: [8nt][4ks][64][8]
  int t = threadIdx.x;
  int w = t >> 6, lane = t & 63;
  int hp = blockIdx.y;                          // head pair: cols [hp*128, +128)
  {
    const uint4* src = (const uint4*)(W1frag + (size_t)hp * 16384);
    uint4* dstp = (uint4*)Bls;
    for (int i = t; i < 2048; i += 256) dstp[i] = src[i];
  }
  __syncthreads();

  int quad = lane >> 4, l16 = lane & 15;
  int rowbase = blockIdx.x * 128 + w * 32;

  short8 afr[2][4];
#pragma unroll
  for (int mt = 0; mt < 2; ++mt) {
    int r = rowbase + mt * 16 + l16; if (r >= N) r = N - 1;
    const unsigned short* rp = xbf + (size_t)r * 128 + quad * 8;
#pragma unroll
    for (int ks = 0; ks < 4; ++ks)
      afr[mt][ks] = *(const short8*)(rp + ks * 32);
  }

  floatx4 acc[2][8] = {};
#pragma unroll
  for (int nt = 0; nt < 8; ++nt) {
#pragma unroll
    for (int ks = 0; ks < 4; ++ks) {
      short8 b = *(const short8*)&Bls[((nt * 4 + ks) * 64 + lane) * 8];
      acc[0][nt] = __builtin_amdgcn_mfma_f32_16x16x32_bf16(afr[0][ks], b, acc[0][nt], 0, 0, 0);
      acc[1][nt] = __builtin_amdgcn_mfma_f32_16x16x32_bf16(afr[1][ks], b, acc[1][nt], 0, 0, 0);
    }
  }

  float asw[8], adw[8];
#pragma unroll
  for (int nt = 0; nt < 8; ++nt) {
    asw[nt] = att_src[hp * 128 + nt * 16 + l16];
    adw[nt] = att_dst[hp * 128 + nt * 16 + l16];
  }
#pragma unroll
  for (int mt = 0; mt < 2; ++mt) {
    float ps[2][4] = {}, pd[2][4] = {};
#pragma unroll
    for (int nt = 0; nt < 8; ++nt) {
      int hl = nt >> 2;
#pragma unroll
      for (int r = 0; r < 4; ++r) {
        float v = acc[mt][nt][r];
        int row = rowbase + mt * 16 + quad * 4 + r;
        if (row < N)
          h1[(size_t)row * 512 + hp * 128 + nt * 16 + l16] = f2bbits(v);
        ps[hl][r] += v * asw[nt];
        pd[hl][r] += v * adw[nt];
      }
    }
#pragma unroll
    for (int hl = 0; hl < 2; ++hl)
#pragma unroll
      for (int r = 0; r < 4; ++r) {
        float p = ps[hl][r], q = pd[hl][r];
#pragma unroll
        for (int off = 1; off < 16; off <<= 1) {
          p += __shfl_xor(p, off);
          q += __shfl_xor(q, off);
        }
        int row = rowbase + mt * 16 + quad * 4 + r;
        if (l16 == 0 && row < N) {
          a_s[(size_t)row * 8 + hp * 2 + hl] = p;
          a_d[(size_t)row * 8 + hp * 2 + hl] = q;
        }
      }
  }
}

// ---------- layer 2: MFMA bf16 GEMM + fused attention coefs ----------
// h2[N,64] = out1[N,512] @ W2[512,64]. Block: 128 rows; wave: 32 rows x 64 cols.
__global__ __launch_bounds__(256) void gemm2_mfma_kernel(
    const unsigned short* __restrict__ x2bf,    // N x 512 bf16
    const unsigned short* __restrict__ W2frag,  // [16ks][4nt][64][8] bf16
    const float* __restrict__ att_src,          // 64
    const float* __restrict__ att_dst,
    float* __restrict__ h2,                     // N x 64 f32
    float* __restrict__ a_s, float* __restrict__ a_d,  // N
    int N) {
  __shared__ unsigned short Bls[32768];         // 64 KB
  int t = threadIdx.x;
  int w = t >> 6, lane = t & 63;
  {
    const uint4* src = (const uint4*)W2frag;
    uint4* dstp = (uint4*)Bls;
    for (int i = t; i < 4096; i += 256) dstp[i] = src[i];
  }
  __syncthreads();

  int quad = lane >> 4, l16 = lane & 15;
  int rowbase = blockIdx.x * 128 + w * 32;

  floatx4 acc[2][4] = {};
  int r0 = rowbase + l16;      if (r0 >= N) r0 = N - 1;
  int r1 = rowbase + 16 + l16; if (r1 >= N) r1 = N - 1;
  const unsigned short* p0 = x2bf + (size_t)r0 * 512 + quad * 8;
  const unsigned short* p1 = x2bf + (size_t)r1 * 512 + quad * 8;
#pragma unroll
  for (int ks = 0; ks < 16; ++ks) {
    short8 a0 = *(const short8*)(p0 + ks * 32);
    short8 a1 = *(const short8*)(p1 + ks * 32);
#pragma unroll
    for (int nt = 0; nt < 4; ++nt) {
      short8 b = *(const short8*)&Bls[((ks * 4 + nt) * 64 + lane) * 8];
      acc[0][nt] = __builtin_amdgcn_mfma_f32_16x16x32_bf16(a0, b, acc[0][nt], 0, 0, 0);
      acc[1][nt] = __builtin_amdgcn_mfma_f32_16x16x32_bf16(a1, b, acc[1][nt], 0, 0, 0);
    }
  }

  float asw[4], adw[4];
#pragma unroll
  for (int nt = 0; nt < 4; ++nt) {
    asw[nt] = att_src[nt * 16 + l16];
    adw[nt] = att_dst[nt * 16 + l16];
  }
#pragma unroll
  for (int mt = 0; mt < 2; ++mt) {
    float ps[4] = {}, pd[4] = {};
#pragma unroll
    for (int nt = 0; nt < 4; ++nt)
#pragma unroll
      for (int r = 0; r < 4; ++r) {
        float v = acc[mt][nt][r];
        int row = rowbase + mt * 16 + quad * 4 + r;
        if (row < N) h2[(size_t)row * 64 + nt * 16 + l16] = v;
        ps[r] += v * asw[nt];
        pd[r] += v * adw[nt];
      }
#pragma unroll
    for (int r = 0; r < 4; ++r) {
      float p = ps[r], q = pd[r];
#pragma unroll
      for (int off = 1; off < 16; off <<= 1) {
        p += __shfl_xor(p, off);
        q += __shfl_xor(q, off);
      }
      int row = rowbase + mt * 16 + quad * 4 + r;
      if (l16 == 0 && row < N) {
        a_s[row] = p;
        a_d[row] = q;
      }
    }
  }
}

// ---------- single-pass GAT aggregation, H=8, bf16 in AND out ----------
__global__ void gat_agg8_kernel(const int* __restrict__ rowptr,
                                const int* __restrict__ col,
                                const float* __restrict__ a_s,
                                const float* __restrict__ a_d,
                                const unsigned short* __restrict__ hfeat,
                                const float* __restrict__ bias,
                                unsigned short* __restrict__ out, int N) {
  int wave = threadIdx.x >> 6, lane = threadIdx.x & 63;
  int d = blockIdx.x * 4 + wave;
  if (d >= N) return;
  int beg = rowptr[d], end = rowptr[d + 1];
  int hh = lane >> 3;
  float adh = a_d[(size_t)d * 8 + hh];

  const uint4* hf = (const uint4*)hfeat;
  float acc[8] = {};
  float wsum = 0.f;
#pragma unroll 2
  for (int i = beg; i < end; ++i) {
    int s = col[i];                          // wave-uniform
    float e = a_s[(size_t)s * 8 + hh] + adh;
    e = e > 0.f ? e : NEG * e;
    float wv = __expf(e);
    wsum += wv;
    uint4 q = hf[(size_t)s * 64 + lane];
    acc[0] += wv * blo(q.x); acc[1] += wv * bhi(q.x);
    acc[2] += wv * blo(q.y); acc[3] += wv * bhi(q.y);
    acc[4] += wv * blo(q.z); acc[5] += wv * bhi(q.z);
    acc[6] += wv * blo(q.w); acc[7] += wv * bhi(q.w);
  }
  float winv = 1.f / (wsum + 1e-16f);
  const float4* b4 = (const float4*)bias;
  float4 b0 = b4[2 * lane], b1 = b4[2 * lane + 1];
  float v0 = elu1(acc[0] * winv + b0.x), v1 = elu1(acc[1] * winv + b0.y);
  float v2 = elu1(acc[2] * winv + b0.z), v3 = elu1(acc[3] * winv + b0.w);
  float v4 = elu1(acc[4] * winv + b1.x), v5 = elu1(acc[5] * winv + b1.y);
  float v6 = elu1(acc[6] * winv + b1.z), v7 = elu1(acc[7] * winv + b1.w);
  uint4 o;
  o.x = pack2(v0, v1); o.y = pack2(v2, v3);
  o.z = pack2(v4, v5); o.w = pack2(v6, v7);
  ((uint4*)out)[(size_t)d * 64 + lane] = o;   // channels 8*lane..+7
}

// single-pass, H=1: lane = channel.
__global__ void gat_agg1_kernel(const int* __restrict__ rowptr,
                                const int* __restrict__ col,
                                const float* __restrict__ a_s,
                                const float* __restrict__ a_d,
                                const float* __restrict__ hfeat,
                                const float* __restrict__ bias,
                                float* __restrict__ out, int N) {
  int wave = threadIdx.x >> 6, lane = threadIdx.x & 63;
  int d = blockIdx.x * 4 + wave;
  if (d >= N) return;
  int beg = rowptr[d], end = rowptr[d + 1];
  float adv = a_d[d];
  float acc = 0.f, wsum = 0.f;
#pragma unroll 2
  for (int i = beg; i < end; ++i) {
    int s = col[i];
    float v = a_s[s] + adv;
    v = v > 0.f ? v : NEG * v;
    float wv = __expf(v);
    wsum += wv;
    acc += wv * hfeat[(size_t)s * 64 + lane];
  }
  out[(size_t)d * 64 + lane] = elu1(acc / (wsum + 1e-16f) + bias[lane]);
}

// ---------- pooling (batch sorted) ----------
__global__ void pool_kernel(const float* __restrict__ out2,
                            const int* __restrict__ batch,
                            float* __restrict__ pooled, int N) {
  int wave = threadIdx.x >> 6, lane = threadIdx.x & 63;
  int seg = blockIdx.x * 4 + wave;
  int start = seg * 128;
  if (start >= N) return;
  int end = min(start + 128, N);
  int cur = batch[start];
  float acc = 0.f;
  for (int n = start; n < end; ++n) {
    int bn = batch[n];
    if (bn != cur) {
      unsafeAtomicAdd(&pooled[cur * 64 + lane], acc);
      acc = 0.f; cur = bn;
    }
    acc += out2[(size_t)n * 64 + lane];
  }
  unsafeAtomicAdd(&pooled[cur * 64 + lane], acc);
}

// ---------- MLP head + log_softmax ----------
__global__ void head_kernel(const float* __restrict__ pooled,
                            const float* __restrict__ lin1_w,
                            const float* __restrict__ lin1_b,
                            const float* __restrict__ lin2_w,
                            const float* __restrict__ lin2_b,
                            const int* __restrict__ flag,
                            void* __restrict__ outv) {
  __shared__ float P[B * C];
  __shared__ float Z[B * C];
  __shared__ float L[B * K];
  int t = threadIdx.x;  // 512
  for (int i = t; i < B * C; i += 512) P[i] = pooled[i];
  __syncthreads();
  for (int i = t; i < B * C; i += 512) {
    int r = i >> 6, c = i & 63;
    float acc = lin1_b[c];
    for (int k = 0; k < C; ++k) acc += P[r * C + k] * lin1_w[k * C + c];
    Z[i] = elu1(acc);
  }
  __syncthreads();
  for (int i = t; i < B * K; i += 512) {
    int r = i / K, c = i - r * K;
    float acc = lin2_b[c];
    for (int k = 0; k < C; ++k) acc += Z[r * C + k] * lin2_w[k * K + c];
    L[i] = acc;
  }
  __syncthreads();
  if (t < B) {
    float mx = -1e30f;
    for (int c = 0; c < K; ++c) mx = fmaxf(mx, L[t * K + c]);
    float s = 0.f;
    for (int c = 0; c < K; ++c) s += __expf(L[t * K + c] - mx);
    float lse = mx + __logf(s);
    int isbf = *flag;
    for (int c = 0; c < K; ++c) {
      float val = L[t * K + c] - lse;
      if (isbf) ((__hip_bfloat16*)outv)[t * K + c] = __float2bfloat16(val);
      else      ((float*)outv)[t * K + c] = val;
    }
  }
}

extern "C" void kernel_launch(void* const* d_in, const int* in_sizes, int n_in,
                              void* d_out, int out_size, void* d_ws, size_t ws_size,
                              hipStream_t stream) {
  const void* x_raw = d_in[0];
  const int*  ei    = (const int*)d_in[1];
  const int*  batch = (const int*)d_in[2];

  const int N    = in_sizes[2];
  const int E    = in_sizes[1] / 2;
  const int Etot = E + N;
  const int nb   = (N + 255) / 256;

  int*   flag = (int*)d_ws;
  float* ws   = (float*)d_ws;
  size_t off  = 16;

  float* wts = ws + off; off += 104848;
  float* as1w = wts + 65536;
  float* ad1w = wts + 66048;
  float* b1w  = wts + 66560;
  float* as2w = wts + 99840;
  float* ad2w = wts + 99904;
  float* b2w  = wts + 99968;
  float* l1w  = wts + 100032;
  float* l1b  = wts + 104128;
  float* l2w  = wts + 104192;
  float* l2b  = wts + 104832;

  unsigned short* xbf    = (unsigned short*)(ws + off); off += (size_t)N * 64;   // N*128 bf16
  unsigned short* w1frag = (unsigned short*)(ws + off); off += 32768;            // 65536 bf16
  unsigned short* w2frag = (unsigned short*)(ws + off); off += 16384;            // 32768 bf16
  unsigned short* h1bf   = (unsigned short*)(ws + off); off += (size_t)N * 256;  // N*512 bf16
  unsigned short* out1bf = (unsigned short*)(ws + off); off += (size_t)N * 256;  // N*512 bf16
  float* h2   = ws + off; off += (size_t)N * 64;
  float* out2 = ws + off; off += (size_t)N * 64;
  float* as1  = ws + off; off += (size_t)N * H1;
  float* ad1  = ws + off; off += (size_t)N * H1;
  float* as2  = ws + off; off += (size_t)N;
  float* ad2  = ws + off; off += (size_t)N;
  float* pooled = ws + off; off += (size_t)B * C;

  int* ibase  = (int*)(ws + off);
  int* deg    = ibase;                 ibase += N;
  int* cursor = ibase;                 ibase += N;
  int* rowptr = ibase;                 ibase += N + 1;
  int* locals = ibase;                 ibase += N;
  int* bsum   = ibase;                 ibase += 256;
  int* col    = ibase;                 ibase += Etot;

  // ---- dtype detect + canonicalize ----
  detect_kernel<<<1, 64, 0, stream>>>(x_raw, flag);
  {
    int n = in_sizes[0];
    int grid = (n + 255) / 256; if (grid > 4096) grid = 4096;
    conv_x_kernel<<<grid, 256, 0, stream>>>(x_raw, xbf, n, flag);
  }
  conv_wts_kernel<<<256, 256, 0, stream>>>(d_in[3], d_in[4], d_in[5], d_in[6],
                                           d_in[7], d_in[8], d_in[9], d_in[10],
                                           d_in[11], d_in[12], d_in[13], d_in[14],
                                           wts, flag);
  prep_frags_kernel<<<48, 256, 0, stream>>>(d_in[3], d_in[7], w1frag, w2frag, flag);

  // ---- CSR build ----
  hipMemsetAsync(deg, 0, (size_t)N * 4, stream);
  hipMemsetAsync(pooled, 0, (size_t)B * C * 4, stream);
  deg_count_kernel<<<(Etot + 255) / 256, 256, 0, stream>>>(ei, E, Etot, deg);
  scan_block_kernel<<<nb, 256, 0, stream>>>(deg, locals, bsum, N);
  scan_sums_kernel<<<1, 256, 0, stream>>>(bsum, nb);
  scan_add_kernel<<<nb, 256, 0, stream>>>(locals, bsum, rowptr, cursor, N, Etot);
  csr_fill_kernel<<<(Etot + 255) / 256, 256, 0, stream>>>(ei, E, Etot, cursor, col);

  // ---- layer 1: MFMA GEMM + fused attn coefs ----
  {
    dim3 grid((N + 127) / 128, 4);
    gemm1_mfma_kernel<<<grid, 256, 0, stream>>>(xbf, w1frag, as1w, ad1w,
                                                h1bf, as1, ad1, N);
  }
  gat_agg8_kernel<<<(N + 3) / 4, 256, 0, stream>>>(rowptr, col, as1, ad1, h1bf, b1w, out1bf, N);

  // ---- layer 2: MFMA GEMM + fused attn coefs ----
  gemm2_mfma_kernel<<<(N + 127) / 128, 256, 0, stream>>>(out1bf, w2frag, as2w, ad2w,
                                                         h2, as2, ad2, N);
  gat_agg1_kernel<<<(N + 3) / 4, 256, 0, stream>>>(rowptr, col, as2, ad2, h2, b2w, out2, N);

  // ---- pool + head ----
  pool_kernel<<<(N + 511) / 512, 256, 0, stream>>>(out2, batch, pooled, N);
  head_kernel<<<1, 512, 0, stream>>>(pooled, l1w, l1b, l2w, l2b, flag, (void*)d_out);
}